// Round 3
// 398.649 us; speedup vs baseline: 1.0881x; 1.0881x over previous
//
#include <hip/hip_runtime.h>
#include <hip/hip_bf16.h>

typedef __hip_bfloat16 bf16;
typedef __attribute__((ext_vector_type(8))) short bf16x8;
typedef __attribute__((ext_vector_type(4))) short bf16x4;
typedef __attribute__((ext_vector_type(4))) float f32x4;

constexpr int BLK = 256;
constexpr int SCAN2_T = 512;

__device__ inline float b2f(bf16 h) { return __bfloat162float(h); }

// bf16 (as raw short) -> f32 : pure bit shift
__device__ inline float s2f(short s) {
    union { unsigned u; float f; } z;
    z.u = ((unsigned)(unsigned short)s) << 16;
    return z.f;
}
__device__ inline short f2s(float f) {
    union { bf16 h; short s; } u;
    u.h = __float2bfloat16(f);
    return u.s;
}

// --- CSR build ------------------------------------------------------------
// Pass 1: degree count with RETURNING atomic; rank of each edge within its
// dst bucket goes to epos[t] (coalesced write). Fill then needs no atomic.
__global__ void count_kernel(const int* __restrict__ dst, int* __restrict__ deg,
                             int* __restrict__ epos, int E) {
    int t = blockIdx.x * blockDim.x + threadIdx.x;
    if (t < E) epos[t] = atomicAdd(&deg[dst[t]], 1);
}

// scan level 1 (+ fused dinv): per-block exclusive scan of deg
__global__ void scan1_kernel(const int* __restrict__ deg, int* __restrict__ row_ptr,
                             int* __restrict__ bsum, float* __restrict__ dinv, int n) {
    __shared__ int s[BLK];
    int t = blockIdx.x * BLK + threadIdx.x;
    int v = (t < n) ? deg[t] : 0;
    if (t < n) dinv[t] = rsqrtf((float)v + 1.0f);
    s[threadIdx.x] = v;
    __syncthreads();
    for (int off = 1; off < BLK; off <<= 1) {
        int add = (threadIdx.x >= off) ? s[threadIdx.x - off] : 0;
        __syncthreads();
        s[threadIdx.x] += add;
        __syncthreads();
    }
    if (t < n) row_ptr[t] = s[threadIdx.x] - v;
    if (threadIdx.x == BLK - 1) bsum[blockIdx.x] = s[BLK - 1];
}

__global__ void scan2_kernel(int* __restrict__ bsum, int nb) {
    __shared__ int s[SCAN2_T];
    int t = threadIdx.x;
    int v = (t < nb) ? bsum[t] : 0;
    s[t] = v;
    __syncthreads();
    for (int off = 1; off < SCAN2_T; off <<= 1) {
        int add = (t >= off) ? s[t - off] : 0;
        __syncthreads();
        s[t] += add;
        __syncthreads();
    }
    if (t < nb) bsum[t] = s[t] - v;
}

__global__ void scan3_kernel(int* __restrict__ row_ptr, const int* __restrict__ bsum, int n) {
    int t = blockIdx.x * BLK + threadIdx.x;
    if (t < n) row_ptr[t] += bsum[blockIdx.x];
}

// Pass 2: atomic-free fill, non-temporal scatter store (no L2 dirty-line thrash)
__global__ void fill_kernel(const int* __restrict__ src, const int* __restrict__ dst,
                            const int* __restrict__ row_ptr, const int* __restrict__ epos,
                            int* __restrict__ col, int E) {
    int t = blockIdx.x * blockDim.x + threadIdx.x;
    if (t >= E) return;
    int pos = row_ptr[dst[t]] + epos[t];
    __builtin_nontemporal_store(src[t], &col[pos]);
}

// --- all three weights -> bf16 transposed, one launch ---------------------
__global__ void wconv_all(const float* __restrict__ W1, const float* __restrict__ W2,
                          const float* __restrict__ W3, bf16* __restrict__ WT1,
                          bf16* __restrict__ WT2, bf16* __restrict__ WT3) {
    int idx = blockIdx.x * blockDim.x + threadIdx.x;
    if (idx < 4096) {
        int k = idx >> 6, c = idx & 63;
        WT1[c * 64 + k] = __float2bfloat16(W1[idx]);
    } else if (idx < 8192) {
        int i = idx - 4096, k = i >> 6, c = i & 63;
        WT2[c * 64 + k] = __float2bfloat16(W2[i]);
    } else if (idx < 10240) {
        int i = idx - 8192, k = i >> 5, c = i & 31;
        WT3[c * 64 + k] = __float2bfloat16(W3[i]);
    }
}

// --- MFMA GEMM: hlin[r,c] = bf16( dinv[r] * sum_k in[r,k]*W[k,c] ) --------
// 16x16x32 bf16. Block = 4 waves x 16 rows. C/D: col=lane&15, row=quad*4+reg.
template <int DOUT, bool AF32>
__global__ void mfma_gemm(const void* __restrict__ inv, const bf16* __restrict__ WT,
                          const float* __restrict__ dinv, bf16* __restrict__ hlin, int n) {
    constexpr int NT = DOUT / 16;
    const int lane = threadIdx.x & 63;
    const int wave = threadIdx.x >> 6;
    const int q = lane >> 4;
    const int l16 = lane & 15;
    const int row0 = blockIdx.x * 64 + wave * 16;

    int arow = row0 + l16;
    if (arow >= n) arow = n - 1;

    bf16x8 a0, a1;
    if (AF32) {
        const float* in = (const float*)inv;
        const float* p = in + (size_t)arow * 64 + q * 8;
        float4 f0 = *(const float4*)(p);
        float4 f1 = *(const float4*)(p + 4);
        float4 g0 = *(const float4*)(p + 32);
        float4 g1 = *(const float4*)(p + 36);
        bf16 t0[8] = {__float2bfloat16(f0.x), __float2bfloat16(f0.y), __float2bfloat16(f0.z), __float2bfloat16(f0.w),
                      __float2bfloat16(f1.x), __float2bfloat16(f1.y), __float2bfloat16(f1.z), __float2bfloat16(f1.w)};
        bf16 t1[8] = {__float2bfloat16(g0.x), __float2bfloat16(g0.y), __float2bfloat16(g0.z), __float2bfloat16(g0.w),
                      __float2bfloat16(g1.x), __float2bfloat16(g1.y), __float2bfloat16(g1.z), __float2bfloat16(g1.w)};
        __builtin_memcpy(&a0, t0, 16);
        __builtin_memcpy(&a1, t1, 16);
    } else {
        const bf16* in = (const bf16*)inv;
        a0 = *(const bf16x8*)(in + (size_t)arow * 64 + q * 8);
        a1 = *(const bf16x8*)(in + (size_t)arow * 64 + 32 + q * 8);
    }

    f32x4 acc[NT];
#pragma unroll
    for (int ct = 0; ct < NT; ++ct) {
        const bf16* wrow = WT + (size_t)(ct * 16 + l16) * 64 + q * 8;
        bf16x8 b0 = *(const bf16x8*)(wrow);
        bf16x8 b1 = *(const bf16x8*)(wrow + 32);
        f32x4 c = {0.f, 0.f, 0.f, 0.f};
        c = __builtin_amdgcn_mfma_f32_16x16x32_bf16(a0, b0, c, 0, 0, 0);
        c = __builtin_amdgcn_mfma_f32_16x16x32_bf16(a1, b1, c, 0, 0, 0);
        acc[ct] = c;
    }

    float dv[4];
#pragma unroll
    for (int r = 0; r < 4; ++r) {
        int rr = row0 + q * 4 + r;
        dv[r] = (rr < n) ? dinv[rr] : 0.0f;
    }
#pragma unroll
    for (int ct = 0; ct < NT; ++ct) {
#pragma unroll
        for (int r = 0; r < 4; ++r) {
            int rr = row0 + q * 4 + r;
            if (rr < n)
                hlin[(size_t)rr * DOUT + ct * 16 + l16] = __float2bfloat16(acc[ct][r] * dv[r]);
        }
    }
}

// --- Pull aggregation, 64 feats -------------------------------------------
// Wave per node. 8 lanes per edge x dwordx4 (16B/lane): one gather instr
// covers 8 edges (1 KB payload) vs 8 x 128B before. Lane (g=lane>>3,
// fl=lane&7) accumulates features fl*8..fl*8+7 for edge-group g; 3-round
// shfl_xor butterfly (8/16/32) combines groups at node end.
template <bool LEAKY>
__global__ void agg64_kernel(const int* __restrict__ row_ptr, const int* __restrict__ deg,
                             const int* __restrict__ col, const bf16* __restrict__ hlin,
                             const float* __restrict__ dinv, const float* __restrict__ b,
                             float* __restrict__ out, bf16* __restrict__ actb, int n) {
    int node = (blockIdx.x * blockDim.x + threadIdx.x) >> 6;
    int lane = threadIdx.x & 63;
    if (node >= n) return;
    const int g = lane >> 3;      // edge group 0..7
    const int fl = lane & 7;      // feature block: fl*8 .. fl*8+7

    float acc[8] = {0.f, 0.f, 0.f, 0.f, 0.f, 0.f, 0.f, 0.f};
    if (g == 0) {                 // self loop counted once (pre-scaled in hlin)
        bf16x8 sv = *(const bf16x8*)(hlin + (size_t)node * 64 + (fl << 3));
#pragma unroll
        for (int k = 0; k < 8; ++k) acc[k] = s2f(sv[k]);
    }

    const int beg = row_ptr[node];
    const int end = beg + deg[node];
    int j = beg;
    for (; j + 16 <= end; j += 16) {
        int c0 = col[j + g];
        int c1 = col[j + 8 + g];
        bf16x8 v0 = *(const bf16x8*)(hlin + (size_t)c0 * 64 + (fl << 3));
        bf16x8 v1 = *(const bf16x8*)(hlin + (size_t)c1 * 64 + (fl << 3));
#pragma unroll
        for (int k = 0; k < 8; ++k) acc[k] += s2f(v0[k]) + s2f(v1[k]);
    }
    if (j + 8 <= end) {
        int c = col[j + g];
        bf16x8 v = *(const bf16x8*)(hlin + (size_t)c * 64 + (fl << 3));
#pragma unroll
        for (int k = 0; k < 8; ++k) acc[k] += s2f(v[k]);
        j += 8;
    }
    if (j + g < end) {
        int c = col[j + g];
        bf16x8 v = *(const bf16x8*)(hlin + (size_t)c * 64 + (fl << 3));
#pragma unroll
        for (int k = 0; k < 8; ++k) acc[k] += s2f(v[k]);
    }

    // combine the 8 edge-groups: butterfly over lane bits 3,4,5
#pragma unroll
    for (int k = 0; k < 8; ++k) acc[k] += __shfl_xor(acc[k], 8);
#pragma unroll
    for (int k = 0; k < 8; ++k) acc[k] += __shfl_xor(acc[k], 16);
#pragma unroll
    for (int k = 0; k < 8; ++k) acc[k] += __shfl_xor(acc[k], 32);

    const float dv = dinv[node];
    const float4 bb0 = *(const float4*)(b + (fl << 3));
    const float4 bb1 = *(const float4*)(b + (fl << 3) + 4);
    float vals[8];
    vals[0] = acc[0] * dv + bb0.x;
    vals[1] = acc[1] * dv + bb0.y;
    vals[2] = acc[2] * dv + bb0.z;
    vals[3] = acc[3] * dv + bb0.w;
    vals[4] = acc[4] * dv + bb1.x;
    vals[5] = acc[5] * dv + bb1.y;
    vals[6] = acc[6] * dv + bb1.z;
    vals[7] = acc[7] * dv + bb1.w;
    if (LEAKY) {
#pragma unroll
        for (int k = 0; k < 8; ++k) vals[k] = (vals[k] >= 0.0f) ? vals[k] : 0.01f * vals[k];
    }
    if (g == 0) {                 // 8 lanes x 32B = 256B contiguous per node
        float* op = out + (size_t)node * 64 + (fl << 3);
        f32x4 o0 = {vals[0], vals[1], vals[2], vals[3]};
        f32x4 o1 = {vals[4], vals[5], vals[6], vals[7]};
        __builtin_nontemporal_store(o0, (f32x4*)op);       // out never re-read
        __builtin_nontemporal_store(o1, (f32x4*)(op + 4));
        if (actb) {
            bf16x8 ob;
#pragma unroll
            for (int k = 0; k < 8; ++k) ob[k] = f2s(vals[k]);
            *(bf16x8*)(actb + (size_t)node * 64 + (fl << 3)) = ob;
        }
    }
}

// --- Pull aggregation, 32 feats -------------------------------------------
// Same structure: wave per node, 8 lanes/edge x dwordx2 (8B/lane).
__global__ void agg32_kernel(const int* __restrict__ row_ptr, const int* __restrict__ deg,
                             const int* __restrict__ col, const bf16* __restrict__ hlin,
                             const float* __restrict__ dinv, const float* __restrict__ b,
                             float* __restrict__ out, int n) {
    int node = (blockIdx.x * blockDim.x + threadIdx.x) >> 6;
    int lane = threadIdx.x & 63;
    if (node >= n) return;
    const int g = lane >> 3;      // edge group 0..7
    const int fl = lane & 7;      // feature block: fl*4 .. fl*4+3

    float acc[4] = {0.f, 0.f, 0.f, 0.f};
    if (g == 0) {
        bf16x4 sv = *(const bf16x4*)(hlin + (size_t)node * 32 + (fl << 2));
#pragma unroll
        for (int k = 0; k < 4; ++k) acc[k] = s2f(sv[k]);
    }

    const int beg = row_ptr[node];
    const int end = beg + deg[node];
    int j = beg;
    for (; j + 16 <= end; j += 16) {
        int c0 = col[j + g];
        int c1 = col[j + 8 + g];
        bf16x4 v0 = *(const bf16x4*)(hlin + (size_t)c0 * 32 + (fl << 2));
        bf16x4 v1 = *(const bf16x4*)(hlin + (size_t)c1 * 32 + (fl << 2));
#pragma unroll
        for (int k = 0; k < 4; ++k) acc[k] += s2f(v0[k]) + s2f(v1[k]);
    }
    if (j + 8 <= end) {
        int c = col[j + g];
        bf16x4 v = *(const bf16x4*)(hlin + (size_t)c * 32 + (fl << 2));
#pragma unroll
        for (int k = 0; k < 4; ++k) acc[k] += s2f(v[k]);
        j += 8;
    }
    if (j + g < end) {
        int c = col[j + g];
        bf16x4 v = *(const bf16x4*)(hlin + (size_t)c * 32 + (fl << 2));
#pragma unroll
        for (int k = 0; k < 4; ++k) acc[k] += s2f(v[k]);
    }

#pragma unroll
    for (int k = 0; k < 4; ++k) acc[k] += __shfl_xor(acc[k], 8);
#pragma unroll
    for (int k = 0; k < 4; ++k) acc[k] += __shfl_xor(acc[k], 16);
#pragma unroll
    for (int k = 0; k < 4; ++k) acc[k] += __shfl_xor(acc[k], 32);

    const float dv = dinv[node];
    const float4 bb = *(const float4*)(b + (fl << 2));
    float vals[4];
    vals[0] = acc[0] * dv + bb.x;
    vals[1] = acc[1] * dv + bb.y;
    vals[2] = acc[2] * dv + bb.z;
    vals[3] = acc[3] * dv + bb.w;
    if (g == 0) {                 // 8 lanes x 16B = 128B contiguous per node
        f32x4 o = {vals[0], vals[1], vals[2], vals[3]};
        __builtin_nontemporal_store(o, (f32x4*)(out + (size_t)node * 32 + (fl << 2)));
    }
}

extern "C" void kernel_launch(void* const* d_in, const int* in_sizes, int n_in,
                              void* d_out, int out_size, void* d_ws, size_t ws_size,
                              hipStream_t stream) {
    const float* x  = (const float*)d_in[0];
    const int*   ei = (const int*)d_in[1];
    const float* W1 = (const float*)d_in[2];
    const float* b1 = (const float*)d_in[3];
    const float* W2 = (const float*)d_in[4];
    const float* b2 = (const float*)d_in[5];
    const float* W3 = (const float*)d_in[6];
    const float* b3 = (const float*)d_in[7];
    float* out = (float*)d_out;

    const int N = in_sizes[0] / 64;   // 100000
    const int E = in_sizes[1] / 2;    // 1600000
    const int* src = ei;
    const int* dst = ei + E;

    char* w = (char*)d_ws;
    auto take = [&](size_t bytes) { char* p = w; w += (bytes + 15) & ~(size_t)15; return p; };
    int*   col     = (int*)take((size_t)E * 4);
    int*   epos    = (int*)take((size_t)E * 4);
    bf16*  hlin    = (bf16*)take((size_t)N * 64 * 2);
    bf16*  actb    = (bf16*)take((size_t)N * 64 * 2);
    bf16*  WT1     = (bf16*)take(64 * 64 * 2);
    bf16*  WT2     = (bf16*)take(64 * 64 * 2);
    bf16*  WT3     = (bf16*)take(32 * 64 * 2);
    int*   deg     = (int*)take((size_t)N * 4);
    int*   row_ptr = (int*)take((size_t)N * 4);
    float* dinv    = (float*)take((size_t)N * 4);
    int*   bsum    = (int*)take((size_t)SCAN2_T * 4);

    float* out0 = out;
    float* out1 = out + (size_t)N * 64;
    float* out2 = out + (size_t)N * 128;

    const int nBlocksN = (N + BLK - 1) / BLK;
    const int nBlocksE = (E + BLK - 1) / BLK;
    const int gemmBlocks = (N + 63) / 64;

    // --- CSR build + norms ---
    hipMemsetAsync(deg, 0, (size_t)N * 4, stream);
    count_kernel<<<nBlocksE, BLK, 0, stream>>>(dst, deg, epos, E);
    scan1_kernel<<<nBlocksN, BLK, 0, stream>>>(deg, row_ptr, bsum, dinv, N);
    scan2_kernel<<<1, SCAN2_T, 0, stream>>>(bsum, nBlocksN);
    scan3_kernel<<<nBlocksN, BLK, 0, stream>>>(row_ptr, bsum, N);
    fill_kernel<<<nBlocksE, BLK, 0, stream>>>(src, dst, row_ptr, epos, col, E);

    // --- weights -> bf16 transposed ---
    wconv_all<<<40, BLK, 0, stream>>>(W1, W2, W3, WT1, WT2, WT3);

    // --- layer 1: 64 -> 64, leaky ---
    mfma_gemm<64, true><<<gemmBlocks, BLK, 0, stream>>>(x, WT1, dinv, hlin, N);
    agg64_kernel<true><<<((size_t)N * 64 + BLK - 1) / BLK, BLK, 0, stream>>>(
        row_ptr, deg, col, hlin, dinv, b1, out0, actb, N);

    // --- layer 2: 64 -> 64, leaky ---
    mfma_gemm<64, false><<<gemmBlocks, BLK, 0, stream>>>(actb, WT2, dinv, hlin, N);
    agg64_kernel<true><<<((size_t)N * 64 + BLK - 1) / BLK, BLK, 0, stream>>>(
        row_ptr, deg, col, hlin, dinv, b2, out1, actb, N);

    // --- layer 3: 64 -> 32, no activation ---
    mfma_gemm<32, false><<<gemmBlocks, BLK, 0, stream>>>(actb, WT3, dinv, hlin, N);
    agg32_kernel<<<((size_t)N * 64 + BLK - 1) / BLK, BLK, 0, stream>>>(
        row_ptr, deg, col, hlin, dinv, b3, out2, N);
}

// Round 4
// 314.931 us; speedup vs baseline: 1.3774x; 1.2658x over previous
//
#include <hip/hip_runtime.h>
#include <hip/hip_bf16.h>

typedef __hip_bfloat16 bf16;
typedef __attribute__((ext_vector_type(8))) short bf16x8;
typedef __attribute__((ext_vector_type(4))) short bf16x4;
typedef __attribute__((ext_vector_type(4))) float f32x4;

constexpr int BLK = 256;
constexpr int SCAN2_T = 512;
constexpr int NBLK = 400;      // edge-partition blocks for hist/scatter
// buckets: dst>>8, 256 nodes per bucket. Requires N <= 512*256 = 131072.

__device__ inline float s2f(short s) {
    union { unsigned u; float f; } z;
    z.u = ((unsigned)(unsigned short)s) << 16;
    return z.f;
}
__device__ inline short f2s(float f) {
    union { bf16 h; short s; } u;
    u.h = __float2bfloat16(f);
    return u.s;
}

// --- CSR build via bucketed counting sort (no global atomics) -------------
// Phase A: per-block LDS histogram of dst buckets.
__global__ void bucket_hist(const int* __restrict__ dst, int* __restrict__ blockhist,
                            int E, int EPB, int NB) {
    __shared__ int h[512];
    for (int i = threadIdx.x; i < NB; i += BLK) h[i] = 0;
    __syncthreads();
    int lo = blockIdx.x * EPB;
    int hi = min(E, lo + EPB);
    for (int t = lo + threadIdx.x; t < hi; t += BLK)
        atomicAdd(&h[dst[t] >> 8], 1);
    __syncthreads();
    for (int i = threadIdx.x; i < NB; i += BLK)
        blockhist[i * NBLK + blockIdx.x] = h[i];   // [bucket][blk]
}

// Phase A2: per-bucket exclusive scan over blocks; bucket total out.
__global__ void colscan_kernel(int* __restrict__ blockhist, int* __restrict__ btotal) {
    __shared__ int s[SCAN2_T];
    int b = blockIdx.x;
    int t = threadIdx.x;
    int v = (t < NBLK) ? blockhist[b * NBLK + t] : 0;
    s[t] = v;
    __syncthreads();
    for (int off = 1; off < SCAN2_T; off <<= 1) {
        int add = (t >= off) ? s[t - off] : 0;
        __syncthreads();
        s[t] += add;
        __syncthreads();
    }
    if (t < NBLK) blockhist[b * NBLK + t] = s[t] - v;   // exclusive
    if (t == SCAN2_T - 1) btotal[b] = s[SCAN2_T - 1];   // bucket total
}

// Phase A3 (reused): exclusive scan of bucket totals -> bucket bases (in place).
__global__ void scan2_kernel(int* __restrict__ bsum, int nb) {
    __shared__ int s[SCAN2_T];
    int t = threadIdx.x;
    int v = (t < nb) ? bsum[t] : 0;
    s[t] = v;
    __syncthreads();
    for (int off = 1; off < SCAN2_T; off <<= 1) {
        int add = (t >= off) ? s[t - off] : 0;
        __syncthreads();
        s[t] += add;
        __syncthreads();
    }
    if (t < nb) bsum[t] = s[t] - v;
}

// Phase B: scatter edges into bucket-sorted order via LDS cursors.
__global__ void bucket_scatter(const int* __restrict__ src, const int* __restrict__ dst,
                               const int* __restrict__ blockhist, const int* __restrict__ bbase,
                               int2* __restrict__ ssd, int E, int EPB, int NB) {
    __shared__ int h[512];
    for (int i = threadIdx.x; i < NB; i += BLK)
        h[i] = bbase[i] + blockhist[i * NBLK + blockIdx.x];
    __syncthreads();
    int lo = blockIdx.x * EPB;
    int hi = min(E, lo + EPB);
    for (int t = lo + threadIdx.x; t < hi; t += BLK) {
        int d = dst[t];
        int pos = atomicAdd(&h[d >> 8], 1);    // LDS returning atomic
        int2 e; e.x = src[t]; e.y = d;
        ssd[pos] = e;
    }
}

// Phase C: per-bucket CSR build entirely in LDS; emits col/deg/row_ptr/dinv.
__global__ void bucket_csr(const int2* __restrict__ ssd, const int* __restrict__ bbase,
                           int* __restrict__ col, int* __restrict__ deg,
                           int* __restrict__ row_ptr, float* __restrict__ dinv,
                           int N, int E, int NB) {
    __shared__ int dloc[256];
    __shared__ int ss[256];
    __shared__ int cur[256];
    int b = blockIdx.x;
    int t = threadIdx.x;
    int lo = bbase[b];
    int hi = (b + 1 < NB) ? bbase[b + 1] : E;
    dloc[t] = 0;
    __syncthreads();
    for (int j = lo + t; j < hi; j += BLK)
        atomicAdd(&dloc[ssd[j].y & 255], 1);
    __syncthreads();
    int own = dloc[t];
    ss[t] = own;
    __syncthreads();
    for (int off = 1; off < 256; off <<= 1) {
        int add = (t >= off) ? ss[t - off] : 0;
        __syncthreads();
        ss[t] += add;
        __syncthreads();
    }
    int excl = ss[t] - own;
    cur[t] = lo + excl;
    int node = (b << 8) + t;
    if (node < N) {
        deg[node] = own;
        row_ptr[node] = lo + excl;
        dinv[node] = rsqrtf((float)own + 1.0f);
    }
    __syncthreads();
    for (int j = lo + t; j < hi; j += BLK) {
        int2 e = ssd[j];
        int p = atomicAdd(&cur[e.y & 255], 1);  // LDS returning atomic
        col[p] = e.x;
    }
}

// --- all three weights -> bf16 transposed, one launch ---------------------
__global__ void wconv_all(const float* __restrict__ W1, const float* __restrict__ W2,
                          const float* __restrict__ W3, bf16* __restrict__ WT1,
                          bf16* __restrict__ WT2, bf16* __restrict__ WT3) {
    int idx = blockIdx.x * blockDim.x + threadIdx.x;
    if (idx < 4096) {
        int k = idx >> 6, c = idx & 63;
        WT1[c * 64 + k] = __float2bfloat16(W1[idx]);
    } else if (idx < 8192) {
        int i = idx - 4096, k = i >> 6, c = i & 63;
        WT2[c * 64 + k] = __float2bfloat16(W2[i]);
    } else if (idx < 10240) {
        int i = idx - 8192, k = i >> 5, c = i & 31;
        WT3[c * 64 + k] = __float2bfloat16(W3[i]);
    }
}

// --- MFMA GEMM: hlin[r,c] = bf16( dinv[r] * sum_k in[r,k]*W[k,c] ) --------
// 16x16x32 bf16. Block = 4 waves x 16 rows. C/D: col=lane&15, row=quad*4+reg.
template <int DOUT, bool AF32>
__global__ void mfma_gemm(const void* __restrict__ inv, const bf16* __restrict__ WT,
                          const float* __restrict__ dinv, bf16* __restrict__ hlin, int n) {
    constexpr int NT = DOUT / 16;
    const int lane = threadIdx.x & 63;
    const int wave = threadIdx.x >> 6;
    const int q = lane >> 4;
    const int l16 = lane & 15;
    const int row0 = blockIdx.x * 64 + wave * 16;

    int arow = row0 + l16;
    if (arow >= n) arow = n - 1;

    bf16x8 a0, a1;
    if (AF32) {
        const float* in = (const float*)inv;
        const float* p = in + (size_t)arow * 64 + q * 8;
        float4 f0 = *(const float4*)(p);
        float4 f1 = *(const float4*)(p + 4);
        float4 g0 = *(const float4*)(p + 32);
        float4 g1 = *(const float4*)(p + 36);
        bf16 t0[8] = {__float2bfloat16(f0.x), __float2bfloat16(f0.y), __float2bfloat16(f0.z), __float2bfloat16(f0.w),
                      __float2bfloat16(f1.x), __float2bfloat16(f1.y), __float2bfloat16(f1.z), __float2bfloat16(f1.w)};
        bf16 t1[8] = {__float2bfloat16(g0.x), __float2bfloat16(g0.y), __float2bfloat16(g0.z), __float2bfloat16(g0.w),
                      __float2bfloat16(g1.x), __float2bfloat16(g1.y), __float2bfloat16(g1.z), __float2bfloat16(g1.w)};
        __builtin_memcpy(&a0, t0, 16);
        __builtin_memcpy(&a1, t1, 16);
    } else {
        const bf16* in = (const bf16*)inv;
        a0 = *(const bf16x8*)(in + (size_t)arow * 64 + q * 8);
        a1 = *(const bf16x8*)(in + (size_t)arow * 64 + 32 + q * 8);
    }

    f32x4 acc[NT];
#pragma unroll
    for (int ct = 0; ct < NT; ++ct) {
        const bf16* wrow = WT + (size_t)(ct * 16 + l16) * 64 + q * 8;
        bf16x8 b0 = *(const bf16x8*)(wrow);
        bf16x8 b1 = *(const bf16x8*)(wrow + 32);
        f32x4 c = {0.f, 0.f, 0.f, 0.f};
        c = __builtin_amdgcn_mfma_f32_16x16x32_bf16(a0, b0, c, 0, 0, 0);
        c = __builtin_amdgcn_mfma_f32_16x16x32_bf16(a1, b1, c, 0, 0, 0);
        acc[ct] = c;
    }

    float dv[4];
#pragma unroll
    for (int r = 0; r < 4; ++r) {
        int rr = row0 + q * 4 + r;
        dv[r] = (rr < n) ? dinv[rr] : 0.0f;
    }
#pragma unroll
    for (int ct = 0; ct < NT; ++ct) {
#pragma unroll
        for (int r = 0; r < 4; ++r) {
            int rr = row0 + q * 4 + r;
            if (rr < n)
                hlin[(size_t)rr * DOUT + ct * 16 + l16] = __float2bfloat16(acc[ct][r] * dv[r]);
        }
    }
}

// --- Pull aggregation, 64 feats -------------------------------------------
// Wave per node. 8 lanes per edge x dwordx4 (16B/lane): one gather instr
// covers 8 edges (1 KB payload). Lane (g=lane>>3, fl=lane&7) accumulates
// features fl*8..fl*8+7 for edge-group g; 3-round shfl_xor butterfly
// (8/16/32) combines groups at node end.
template <bool LEAKY>
__global__ void agg64_kernel(const int* __restrict__ row_ptr, const int* __restrict__ deg,
                             const int* __restrict__ col, const bf16* __restrict__ hlin,
                             const float* __restrict__ dinv, const float* __restrict__ b,
                             float* __restrict__ out, bf16* __restrict__ actb, int n) {
    int node = (blockIdx.x * blockDim.x + threadIdx.x) >> 6;
    int lane = threadIdx.x & 63;
    if (node >= n) return;
    const int g = lane >> 3;      // edge group 0..7
    const int fl = lane & 7;      // feature block: fl*8 .. fl*8+7

    float acc[8] = {0.f, 0.f, 0.f, 0.f, 0.f, 0.f, 0.f, 0.f};
    if (g == 0) {                 // self loop counted once (pre-scaled in hlin)
        bf16x8 sv = *(const bf16x8*)(hlin + (size_t)node * 64 + (fl << 3));
#pragma unroll
        for (int k = 0; k < 8; ++k) acc[k] = s2f(sv[k]);
    }

    const int beg = row_ptr[node];
    const int end = beg + deg[node];
    int j = beg;
    for (; j + 16 <= end; j += 16) {
        int c0 = col[j + g];
        int c1 = col[j + 8 + g];
        bf16x8 v0 = *(const bf16x8*)(hlin + (size_t)c0 * 64 + (fl << 3));
        bf16x8 v1 = *(const bf16x8*)(hlin + (size_t)c1 * 64 + (fl << 3));
#pragma unroll
        for (int k = 0; k < 8; ++k) acc[k] += s2f(v0[k]) + s2f(v1[k]);
    }
    if (j + 8 <= end) {
        int c = col[j + g];
        bf16x8 v = *(const bf16x8*)(hlin + (size_t)c * 64 + (fl << 3));
#pragma unroll
        for (int k = 0; k < 8; ++k) acc[k] += s2f(v[k]);
        j += 8;
    }
    if (j + g < end) {
        int c = col[j + g];
        bf16x8 v = *(const bf16x8*)(hlin + (size_t)c * 64 + (fl << 3));
#pragma unroll
        for (int k = 0; k < 8; ++k) acc[k] += s2f(v[k]);
    }

    // combine the 8 edge-groups: butterfly over lane bits 3,4,5
#pragma unroll
    for (int k = 0; k < 8; ++k) acc[k] += __shfl_xor(acc[k], 8);
#pragma unroll
    for (int k = 0; k < 8; ++k) acc[k] += __shfl_xor(acc[k], 16);
#pragma unroll
    for (int k = 0; k < 8; ++k) acc[k] += __shfl_xor(acc[k], 32);

    const float dv = dinv[node];
    const float4 bb0 = *(const float4*)(b + (fl << 3));
    const float4 bb1 = *(const float4*)(b + (fl << 3) + 4);
    float vals[8];
    vals[0] = acc[0] * dv + bb0.x;
    vals[1] = acc[1] * dv + bb0.y;
    vals[2] = acc[2] * dv + bb0.z;
    vals[3] = acc[3] * dv + bb0.w;
    vals[4] = acc[4] * dv + bb1.x;
    vals[5] = acc[5] * dv + bb1.y;
    vals[6] = acc[6] * dv + bb1.z;
    vals[7] = acc[7] * dv + bb1.w;
    if (LEAKY) {
#pragma unroll
        for (int k = 0; k < 8; ++k) vals[k] = (vals[k] >= 0.0f) ? vals[k] : 0.01f * vals[k];
    }
    if (g == 0) {                 // 8 lanes x 32B = 256B contiguous per node
        float* op = out + (size_t)node * 64 + (fl << 3);
        f32x4 o0 = {vals[0], vals[1], vals[2], vals[3]};
        f32x4 o1 = {vals[4], vals[5], vals[6], vals[7]};
        __builtin_nontemporal_store(o0, (f32x4*)op);       // out never re-read
        __builtin_nontemporal_store(o1, (f32x4*)(op + 4));
        if (actb) {
            bf16x8 ob;
#pragma unroll
            for (int k = 0; k < 8; ++k) ob[k] = f2s(vals[k]);
            *(bf16x8*)(actb + (size_t)node * 64 + (fl << 3)) = ob;
        }
    }
}

// --- Pull aggregation, 32 feats -------------------------------------------
// Same structure: wave per node, 8 lanes/edge x dwordx2 (8B/lane).
__global__ void agg32_kernel(const int* __restrict__ row_ptr, const int* __restrict__ deg,
                             const int* __restrict__ col, const bf16* __restrict__ hlin,
                             const float* __restrict__ dinv, const float* __restrict__ b,
                             float* __restrict__ out, int n) {
    int node = (blockIdx.x * blockDim.x + threadIdx.x) >> 6;
    int lane = threadIdx.x & 63;
    if (node >= n) return;
    const int g = lane >> 3;      // edge group 0..7
    const int fl = lane & 7;      // feature block: fl*4 .. fl*4+3

    float acc[4] = {0.f, 0.f, 0.f, 0.f};
    if (g == 0) {
        bf16x4 sv = *(const bf16x4*)(hlin + (size_t)node * 32 + (fl << 2));
#pragma unroll
        for (int k = 0; k < 4; ++k) acc[k] = s2f(sv[k]);
    }

    const int beg = row_ptr[node];
    const int end = beg + deg[node];
    int j = beg;
    for (; j + 16 <= end; j += 16) {
        int c0 = col[j + g];
        int c1 = col[j + 8 + g];
        bf16x4 v0 = *(const bf16x4*)(hlin + (size_t)c0 * 32 + (fl << 2));
        bf16x4 v1 = *(const bf16x4*)(hlin + (size_t)c1 * 32 + (fl << 2));
#pragma unroll
        for (int k = 0; k < 4; ++k) acc[k] += s2f(v0[k]) + s2f(v1[k]);
    }
    if (j + 8 <= end) {
        int c = col[j + g];
        bf16x4 v = *(const bf16x4*)(hlin + (size_t)c * 32 + (fl << 2));
#pragma unroll
        for (int k = 0; k < 4; ++k) acc[k] += s2f(v[k]);
        j += 8;
    }
    if (j + g < end) {
        int c = col[j + g];
        bf16x4 v = *(const bf16x4*)(hlin + (size_t)c * 32 + (fl << 2));
#pragma unroll
        for (int k = 0; k < 4; ++k) acc[k] += s2f(v[k]);
    }

#pragma unroll
    for (int k = 0; k < 4; ++k) acc[k] += __shfl_xor(acc[k], 8);
#pragma unroll
    for (int k = 0; k < 4; ++k) acc[k] += __shfl_xor(acc[k], 16);
#pragma unroll
    for (int k = 0; k < 4; ++k) acc[k] += __shfl_xor(acc[k], 32);

    const float dv = dinv[node];
    const float4 bb = *(const float4*)(b + (fl << 2));
    float vals[4];
    vals[0] = acc[0] * dv + bb.x;
    vals[1] = acc[1] * dv + bb.y;
    vals[2] = acc[2] * dv + bb.z;
    vals[3] = acc[3] * dv + bb.w;
    if (g == 0) {                 // 8 lanes x 16B = 128B contiguous per node
        f32x4 o = {vals[0], vals[1], vals[2], vals[3]};
        __builtin_nontemporal_store(o, (f32x4*)(out + (size_t)node * 32 + (fl << 2)));
    }
}

extern "C" void kernel_launch(void* const* d_in, const int* in_sizes, int n_in,
                              void* d_out, int out_size, void* d_ws, size_t ws_size,
                              hipStream_t stream) {
    const float* x  = (const float*)d_in[0];
    const int*   ei = (const int*)d_in[1];
    const float* W1 = (const float*)d_in[2];
    const float* b1 = (const float*)d_in[3];
    const float* W2 = (const float*)d_in[4];
    const float* b2 = (const float*)d_in[5];
    const float* W3 = (const float*)d_in[6];
    const float* b3 = (const float*)d_in[7];
    float* out = (float*)d_out;

    const int N = in_sizes[0] / 64;   // 100000
    const int E = in_sizes[1] / 2;    // 1600000
    const int* src = ei;
    const int* dst = ei + E;

    const int NB  = (N + 255) >> 8;           // buckets (<=512 for N<=131072)
    const int EPB = (E + NBLK - 1) / NBLK;    // edges per partition block

    char* w = (char*)d_ws;
    auto take = [&](size_t bytes) { char* p = w; w += (bytes + 15) & ~(size_t)15; return p; };
    int*   col       = (int*)take((size_t)E * 4);
    int2*  ssd       = (int2*)take((size_t)E * 8);
    bf16*  hlin      = (bf16*)take((size_t)N * 64 * 2);
    bf16*  actb      = (bf16*)take((size_t)N * 64 * 2);
    bf16*  WT1       = (bf16*)take(64 * 64 * 2);
    bf16*  WT2       = (bf16*)take(64 * 64 * 2);
    bf16*  WT3       = (bf16*)take(32 * 64 * 2);
    int*   deg       = (int*)take((size_t)N * 4);
    int*   row_ptr   = (int*)take((size_t)N * 4);
    float* dinv      = (float*)take((size_t)N * 4);
    int*   blockhist = (int*)take((size_t)NB * NBLK * 4);
    int*   btotal    = (int*)take((size_t)SCAN2_T * 4);

    float* out0 = out;
    float* out1 = out + (size_t)N * 64;
    float* out2 = out + (size_t)N * 128;

    const int gemmBlocks = (N + 63) / 64;

    // --- CSR build: bucketed counting sort, LDS atomics only ---
    bucket_hist<<<NBLK, BLK, 0, stream>>>(dst, blockhist, E, EPB, NB);
    colscan_kernel<<<NB, SCAN2_T, 0, stream>>>(blockhist, btotal);
    scan2_kernel<<<1, SCAN2_T, 0, stream>>>(btotal, NB);       // -> bucket bases
    bucket_scatter<<<NBLK, BLK, 0, stream>>>(src, dst, blockhist, btotal, ssd, E, EPB, NB);
    bucket_csr<<<NB, BLK, 0, stream>>>(ssd, btotal, col, deg, row_ptr, dinv, N, E, NB);

    // --- weights -> bf16 transposed ---
    wconv_all<<<40, BLK, 0, stream>>>(W1, W2, W3, WT1, WT2, WT3);

    // --- layer 1: 64 -> 64, leaky ---
    mfma_gemm<64, true><<<gemmBlocks, BLK, 0, stream>>>(x, WT1, dinv, hlin, N);
    agg64_kernel<true><<<((size_t)N * 64 + BLK - 1) / BLK, BLK, 0, stream>>>(
        row_ptr, deg, col, hlin, dinv, b1, out0, actb, N);

    // --- layer 2: 64 -> 64, leaky ---
    mfma_gemm<64, false><<<gemmBlocks, BLK, 0, stream>>>(actb, WT2, dinv, hlin, N);
    agg64_kernel<true><<<((size_t)N * 64 + BLK - 1) / BLK, BLK, 0, stream>>>(
        row_ptr, deg, col, hlin, dinv, b2, out1, actb, N);

    // --- layer 3: 64 -> 32, no activation ---
    mfma_gemm<32, false><<<gemmBlocks, BLK, 0, stream>>>(actb, WT3, dinv, hlin, N);
    agg32_kernel<<<((size_t)N * 64 + BLK - 1) / BLK, BLK, 0, stream>>>(
        row_ptr, deg, col, hlin, dinv, b3, out2, N);
}

// Round 5
// 295.572 us; speedup vs baseline: 1.4676x; 1.0655x over previous
//
#include <hip/hip_runtime.h>
#include <hip/hip_bf16.h>

typedef __hip_bfloat16 bf16;
typedef __attribute__((ext_vector_type(8))) short bf16x8;
typedef __attribute__((ext_vector_type(4))) short bf16x4;
typedef __attribute__((ext_vector_type(4))) float f32x4;

constexpr int BLK = 256;
constexpr int SCAN2_T = 512;
constexpr int NBLK = 400;      // edge-partition blocks for hist/scatter
// buckets: dst>>8, 256 nodes per bucket. Requires N <= 512*256 = 131072.

__device__ inline float s2f(short s) {
    union { unsigned u; float f; } z;
    z.u = ((unsigned)(unsigned short)s) << 16;
    return z.f;
}
__device__ inline short f2s(float f) {
    union { bf16 h; short s; } u;
    u.h = __float2bfloat16(f);
    return u.s;
}

// --- CSR build via bucketed counting sort (no global atomics) -------------
// Phase A: per-block LDS histogram of dst buckets.
__global__ void bucket_hist(const int* __restrict__ dst, int* __restrict__ blockhist,
                            int E, int EPB, int NB) {
    __shared__ int h[512];
    for (int i = threadIdx.x; i < NB; i += BLK) h[i] = 0;
    __syncthreads();
    int lo = blockIdx.x * EPB;
    int hi = min(E, lo + EPB);
    for (int t = lo + threadIdx.x; t < hi; t += BLK)
        atomicAdd(&h[dst[t] >> 8], 1);
    __syncthreads();
    for (int i = threadIdx.x; i < NB; i += BLK)
        blockhist[i * NBLK + blockIdx.x] = h[i];   // [bucket][blk]
}

// Phase A2: per-bucket exclusive scan over blocks; bucket total out.
__global__ void colscan_kernel(int* __restrict__ blockhist, int* __restrict__ btotal) {
    __shared__ int s[SCAN2_T];
    int b = blockIdx.x;
    int t = threadIdx.x;
    int v = (t < NBLK) ? blockhist[b * NBLK + t] : 0;
    s[t] = v;
    __syncthreads();
    for (int off = 1; off < SCAN2_T; off <<= 1) {
        int add = (t >= off) ? s[t - off] : 0;
        __syncthreads();
        s[t] += add;
        __syncthreads();
    }
    if (t < NBLK) blockhist[b * NBLK + t] = s[t] - v;   // exclusive
    if (t == SCAN2_T - 1) btotal[b] = s[SCAN2_T - 1];   // bucket total
}

// Phase A3 (reused): exclusive scan of bucket totals -> bucket bases (in place).
__global__ void scan2_kernel(int* __restrict__ bsum, int nb) {
    __shared__ int s[SCAN2_T];
    int t = threadIdx.x;
    int v = (t < nb) ? bsum[t] : 0;
    s[t] = v;
    __syncthreads();
    for (int off = 1; off < SCAN2_T; off <<= 1) {
        int add = (t >= off) ? s[t - off] : 0;
        __syncthreads();
        s[t] += add;
        __syncthreads();
    }
    if (t < nb) bsum[t] = s[t] - v;
}

// Phase B: scatter edges into bucket-sorted order via LDS cursors.
__global__ void bucket_scatter(const int* __restrict__ src, const int* __restrict__ dst,
                               const int* __restrict__ blockhist, const int* __restrict__ bbase,
                               int2* __restrict__ ssd, int E, int EPB, int NB) {
    __shared__ int h[512];
    for (int i = threadIdx.x; i < NB; i += BLK)
        h[i] = bbase[i] + blockhist[i * NBLK + blockIdx.x];
    __syncthreads();
    int lo = blockIdx.x * EPB;
    int hi = min(E, lo + EPB);
    for (int t = lo + threadIdx.x; t < hi; t += BLK) {
        int d = dst[t];
        int pos = atomicAdd(&h[d >> 8], 1);    // LDS returning atomic
        int2 e; e.x = src[t]; e.y = d;
        ssd[pos] = e;
    }
}

// Phase C: per-bucket CSR build entirely in LDS; emits col/deg/row_ptr/dinv.
__global__ void bucket_csr(const int2* __restrict__ ssd, const int* __restrict__ bbase,
                           int* __restrict__ col, int* __restrict__ deg,
                           int* __restrict__ row_ptr, float* __restrict__ dinv,
                           int N, int E, int NB) {
    __shared__ int dloc[256];
    __shared__ int ss[256];
    __shared__ int cur[256];
    int b = blockIdx.x;
    int t = threadIdx.x;
    int lo = bbase[b];
    int hi = (b + 1 < NB) ? bbase[b + 1] : E;
    dloc[t] = 0;
    __syncthreads();
    for (int j = lo + t; j < hi; j += BLK)
        atomicAdd(&dloc[ssd[j].y & 255], 1);
    __syncthreads();
    int own = dloc[t];
    ss[t] = own;
    __syncthreads();
    for (int off = 1; off < 256; off <<= 1) {
        int add = (t >= off) ? ss[t - off] : 0;
        __syncthreads();
        ss[t] += add;
        __syncthreads();
    }
    int excl = ss[t] - own;
    cur[t] = lo + excl;
    int node = (b << 8) + t;
    if (node < N) {
        deg[node] = own;
        row_ptr[node] = lo + excl;
        dinv[node] = rsqrtf((float)own + 1.0f);
    }
    __syncthreads();
    for (int j = lo + t; j < hi; j += BLK) {
        int2 e = ssd[j];
        int p = atomicAdd(&cur[e.y & 255], 1);  // LDS returning atomic
        col[p] = e.x;
    }
}

// --- all three weights -> bf16 transposed, one launch ---------------------
__global__ void wconv_all(const float* __restrict__ W1, const float* __restrict__ W2,
                          const float* __restrict__ W3, bf16* __restrict__ WT1,
                          bf16* __restrict__ WT2, bf16* __restrict__ WT3) {
    int idx = blockIdx.x * blockDim.x + threadIdx.x;
    if (idx < 4096) {
        int k = idx >> 6, c = idx & 63;
        WT1[c * 64 + k] = __float2bfloat16(W1[idx]);
    } else if (idx < 8192) {
        int i = idx - 4096, k = i >> 6, c = i & 63;
        WT2[c * 64 + k] = __float2bfloat16(W2[i]);
    } else if (idx < 10240) {
        int i = idx - 8192, k = i >> 5, c = i & 31;
        WT3[c * 64 + k] = __float2bfloat16(W3[i]);
    }
}

// --- MFMA GEMM: hlin[r,c] = bf16( dinv[r] * sum_k in[r,k]*W[k,c] ) --------
// 16x16x32 bf16. Block = 4 waves x 16 rows. C/D: col=lane&15, row=quad*4+reg.
template <int DOUT, bool AF32>
__global__ void mfma_gemm(const void* __restrict__ inv, const bf16* __restrict__ WT,
                          const float* __restrict__ dinv, bf16* __restrict__ hlin, int n) {
    constexpr int NT = DOUT / 16;
    const int lane = threadIdx.x & 63;
    const int wave = threadIdx.x >> 6;
    const int q = lane >> 4;
    const int l16 = lane & 15;
    const int row0 = blockIdx.x * 64 + wave * 16;

    int arow = row0 + l16;
    if (arow >= n) arow = n - 1;

    bf16x8 a0, a1;
    if (AF32) {
        const float* in = (const float*)inv;
        const float* p = in + (size_t)arow * 64 + q * 8;
        float4 f0 = *(const float4*)(p);
        float4 f1 = *(const float4*)(p + 4);
        float4 g0 = *(const float4*)(p + 32);
        float4 g1 = *(const float4*)(p + 36);
        bf16 t0[8] = {__float2bfloat16(f0.x), __float2bfloat16(f0.y), __float2bfloat16(f0.z), __float2bfloat16(f0.w),
                      __float2bfloat16(f1.x), __float2bfloat16(f1.y), __float2bfloat16(f1.z), __float2bfloat16(f1.w)};
        bf16 t1[8] = {__float2bfloat16(g0.x), __float2bfloat16(g0.y), __float2bfloat16(g0.z), __float2bfloat16(g0.w),
                      __float2bfloat16(g1.x), __float2bfloat16(g1.y), __float2bfloat16(g1.z), __float2bfloat16(g1.w)};
        __builtin_memcpy(&a0, t0, 16);
        __builtin_memcpy(&a1, t1, 16);
    } else {
        const bf16* in = (const bf16*)inv;
        a0 = *(const bf16x8*)(in + (size_t)arow * 64 + q * 8);
        a1 = *(const bf16x8*)(in + (size_t)arow * 64 + 32 + q * 8);
    }

    f32x4 acc[NT];
#pragma unroll
    for (int ct = 0; ct < NT; ++ct) {
        const bf16* wrow = WT + (size_t)(ct * 16 + l16) * 64 + q * 8;
        bf16x8 b0 = *(const bf16x8*)(wrow);
        bf16x8 b1 = *(const bf16x8*)(wrow + 32);
        f32x4 c = {0.f, 0.f, 0.f, 0.f};
        c = __builtin_amdgcn_mfma_f32_16x16x32_bf16(a0, b0, c, 0, 0, 0);
        c = __builtin_amdgcn_mfma_f32_16x16x32_bf16(a1, b1, c, 0, 0, 0);
        acc[ct] = c;
    }

    float dv[4];
#pragma unroll
    for (int r = 0; r < 4; ++r) {
        int rr = row0 + q * 4 + r;
        dv[r] = (rr < n) ? dinv[rr] : 0.0f;
    }
#pragma unroll
    for (int ct = 0; ct < NT; ++ct) {
#pragma unroll
        for (int r = 0; r < 4; ++r) {
            int rr = row0 + q * 4 + r;
            if (rr < n)
                hlin[(size_t)rr * DOUT + ct * 16 + l16] = __float2bfloat16(acc[ct][r] * dv[r]);
        }
    }
}

// --- Pull aggregation, 64 feats, 4 nodes per wave -------------------------
// 16 lanes/node = 8 feature-lanes (fl, dwordx4=8 feats) x 2 edge-groups (g).
// Shared loop count = ceil(max_deg_of_4 / 2); inactive lanes gather the
// zeroed PAD row (index n, L1-resident) -- branch-free predication.
// col is prefetched one iteration ahead to break the col->gather chain.
// One butterfly round (xor 8) combines the 2 edge groups.
template <bool LEAKY>
__global__ void agg64_kernel(const int* __restrict__ row_ptr, const int* __restrict__ deg,
                             const int* __restrict__ col, const bf16* __restrict__ hlin,
                             const float* __restrict__ dinv, const float* __restrict__ b,
                             float* __restrict__ out, bf16* __restrict__ actb, int n) {
    const int wid = (blockIdx.x * blockDim.x + threadIdx.x) >> 6;
    const int lane = threadIdx.x & 63;
    const int sub = lane >> 4;           // node slot 0..3
    const int g = (lane >> 3) & 1;       // edge group 0..1
    const int fl = lane & 7;             // feature block fl*8..+7
    const int node = wid * 4 + sub;
    const int PAD = n;                   // zero row (64-feat layout)

    const bool valid = node < n;
    const int nc = valid ? node : n - 1;
    const int beg = row_ptr[nc];
    const int dg = valid ? deg[nc] : 0;
    const int end = beg + dg;

    float acc[8];
    {   // self loop: g==0 lanes read own row; g==1 lanes read zero PAD row
        int c0 = (valid && g == 0) ? node : PAD;
        bf16x8 sv = *(const bf16x8*)(hlin + (size_t)c0 * 64 + (fl << 3));
#pragma unroll
        for (int k = 0; k < 8; ++k) acc[k] = s2f(sv[k]);
    }

    // shared iteration count: max deg over this wave's 4 nodes
    int m = dg;
    m = max(m, __shfl_xor(m, 16));
    m = max(m, __shfl_xor(m, 32));
    const int iters = (m + 1) >> 1;

    int idx = beg + g;
    int cv = col[idx < end ? idx : 0];
    for (int j = 0; j < iters; ++j) {
        const int c = (idx < end) ? cv : PAD;
        idx += 2;
        cv = col[idx < end ? idx : 0];   // prefetch next (dummy safe read on tail)
        bf16x8 v = *(const bf16x8*)(hlin + (size_t)c * 64 + (fl << 3));
#pragma unroll
        for (int k = 0; k < 8; ++k) acc[k] += s2f(v[k]);
    }

    // combine the 2 edge groups
#pragma unroll
    for (int k = 0; k < 8; ++k) acc[k] += __shfl_xor(acc[k], 8);

    const float dv = dinv[nc];
    const float4 bb0 = *(const float4*)(b + (fl << 3));
    const float4 bb1 = *(const float4*)(b + (fl << 3) + 4);
    float vals[8];
    vals[0] = acc[0] * dv + bb0.x;
    vals[1] = acc[1] * dv + bb0.y;
    vals[2] = acc[2] * dv + bb0.z;
    vals[3] = acc[3] * dv + bb0.w;
    vals[4] = acc[4] * dv + bb1.x;
    vals[5] = acc[5] * dv + bb1.y;
    vals[6] = acc[6] * dv + bb1.z;
    vals[7] = acc[7] * dv + bb1.w;
    if (LEAKY) {
#pragma unroll
        for (int k = 0; k < 8; ++k) vals[k] = (vals[k] >= 0.0f) ? vals[k] : 0.01f * vals[k];
    }
    if (valid && g == 0) {               // 4 nodes store in parallel: 1KB/wave
        float* op = out + (size_t)node * 64 + (fl << 3);
        f32x4 o0 = {vals[0], vals[1], vals[2], vals[3]};
        f32x4 o1 = {vals[4], vals[5], vals[6], vals[7]};
        __builtin_nontemporal_store(o0, (f32x4*)op);       // out never re-read
        __builtin_nontemporal_store(o1, (f32x4*)(op + 4));
        if (actb) {
            bf16x8 ob;
#pragma unroll
            for (int k = 0; k < 8; ++k) ob[k] = f2s(vals[k]);
            *(bf16x8*)(actb + (size_t)node * 64 + (fl << 3)) = ob;
        }
    }
}

// --- Pull aggregation, 32 feats, 4 nodes per wave -------------------------
// Same structure with dwordx2 gathers (fl covers 4 feats). PAD row = 2n
// (32-feat layout) aliases the same zeroed halfword region as agg64's PAD.
__global__ void agg32_kernel(const int* __restrict__ row_ptr, const int* __restrict__ deg,
                             const int* __restrict__ col, const bf16* __restrict__ hlin,
                             const float* __restrict__ dinv, const float* __restrict__ b,
                             float* __restrict__ out, int n) {
    const int wid = (blockIdx.x * blockDim.x + threadIdx.x) >> 6;
    const int lane = threadIdx.x & 63;
    const int sub = lane >> 4;
    const int g = (lane >> 3) & 1;
    const int fl = lane & 7;             // feature block fl*4..+3
    const int node = wid * 4 + sub;
    const int PAD = 2 * n;               // zero row (32-feat layout)

    const bool valid = node < n;
    const int nc = valid ? node : n - 1;
    const int beg = row_ptr[nc];
    const int dg = valid ? deg[nc] : 0;
    const int end = beg + dg;

    float acc[4];
    {
        int c0 = (valid && g == 0) ? node : PAD;
        bf16x4 sv = *(const bf16x4*)(hlin + (size_t)c0 * 32 + (fl << 2));
#pragma unroll
        for (int k = 0; k < 4; ++k) acc[k] = s2f(sv[k]);
    }

    int m = dg;
    m = max(m, __shfl_xor(m, 16));
    m = max(m, __shfl_xor(m, 32));
    const int iters = (m + 1) >> 1;

    int idx = beg + g;
    int cv = col[idx < end ? idx : 0];
    for (int j = 0; j < iters; ++j) {
        const int c = (idx < end) ? cv : PAD;
        idx += 2;
        cv = col[idx < end ? idx : 0];
        bf16x4 v = *(const bf16x4*)(hlin + (size_t)c * 32 + (fl << 2));
#pragma unroll
        for (int k = 0; k < 4; ++k) acc[k] += s2f(v[k]);
    }

#pragma unroll
    for (int k = 0; k < 4; ++k) acc[k] += __shfl_xor(acc[k], 8);

    const float dv = dinv[nc];
    const float4 bb = *(const float4*)(b + (fl << 2));
    float vals[4];
    vals[0] = acc[0] * dv + bb.x;
    vals[1] = acc[1] * dv + bb.y;
    vals[2] = acc[2] * dv + bb.z;
    vals[3] = acc[3] * dv + bb.w;
    if (valid && g == 0) {               // 4 x 128B contiguous per wave
        f32x4 o = {vals[0], vals[1], vals[2], vals[3]};
        __builtin_nontemporal_store(o, (f32x4*)(out + (size_t)node * 32 + (fl << 2)));
    }
}

extern "C" void kernel_launch(void* const* d_in, const int* in_sizes, int n_in,
                              void* d_out, int out_size, void* d_ws, size_t ws_size,
                              hipStream_t stream) {
    const float* x  = (const float*)d_in[0];
    const int*   ei = (const int*)d_in[1];
    const float* W1 = (const float*)d_in[2];
    const float* b1 = (const float*)d_in[3];
    const float* W2 = (const float*)d_in[4];
    const float* b2 = (const float*)d_in[5];
    const float* W3 = (const float*)d_in[6];
    const float* b3 = (const float*)d_in[7];
    float* out = (float*)d_out;

    const int N = in_sizes[0] / 64;   // 100000
    const int E = in_sizes[1] / 2;    // 1600000
    const int* src = ei;
    const int* dst = ei + E;

    const int NB  = (N + 255) >> 8;           // buckets (<=512 for N<=131072)
    const int EPB = (E + NBLK - 1) / NBLK;    // edges per partition block

    char* w = (char*)d_ws;
    auto take = [&](size_t bytes) { char* p = w; w += (bytes + 15) & ~(size_t)15; return p; };
    int*   col       = (int*)take((size_t)E * 4);
    int2*  ssd       = (int2*)take((size_t)E * 8);
    bf16*  hlin      = (bf16*)take(((size_t)N * 64 + 64) * 2);  // +64 halfwords: PAD row
    bf16*  actb      = (bf16*)take((size_t)N * 64 * 2);
    bf16*  WT1       = (bf16*)take(64 * 64 * 2);
    bf16*  WT2       = (bf16*)take(64 * 64 * 2);
    bf16*  WT3       = (bf16*)take(32 * 64 * 2);
    int*   deg       = (int*)take((size_t)N * 4);
    int*   row_ptr   = (int*)take((size_t)N * 4);
    float* dinv      = (float*)take((size_t)N * 4);
    int*   blockhist = (int*)take((size_t)NB * NBLK * 4);
    int*   btotal    = (int*)take((size_t)SCAN2_T * 4);

    float* out0 = out;
    float* out1 = out + (size_t)N * 64;
    float* out2 = out + (size_t)N * 128;

    const int gemmBlocks = (N + 63) / 64;
    const int aggWaves = (N + 3) / 4;
    const int aggBlocks = (aggWaves * 64 + BLK - 1) / BLK;

    // zero the PAD row: halfwords [64N, 64N+64) -- covers agg64 PAD=N
    // (reads [64N,64N+64)) and agg32 PAD=2N (reads [64N,64N+32)); this
    // region is never written by any gemm (they write < 64N halfwords).
    hipMemsetAsync(hlin + (size_t)N * 64, 0, 128, stream);

    // --- CSR build: bucketed counting sort, LDS atomics only ---
    bucket_hist<<<NBLK, BLK, 0, stream>>>(dst, blockhist, E, EPB, NB);
    colscan_kernel<<<NB, SCAN2_T, 0, stream>>>(blockhist, btotal);
    scan2_kernel<<<1, SCAN2_T, 0, stream>>>(btotal, NB);       // -> bucket bases
    bucket_scatter<<<NBLK, BLK, 0, stream>>>(src, dst, blockhist, btotal, ssd, E, EPB, NB);
    bucket_csr<<<NB, BLK, 0, stream>>>(ssd, btotal, col, deg, row_ptr, dinv, N, E, NB);

    // --- weights -> bf16 transposed ---
    wconv_all<<<40, BLK, 0, stream>>>(W1, W2, W3, WT1, WT2, WT3);

    // --- layer 1: 64 -> 64, leaky ---
    mfma_gemm<64, true><<<gemmBlocks, BLK, 0, stream>>>(x, WT1, dinv, hlin, N);
    agg64_kernel<true><<<aggBlocks, BLK, 0, stream>>>(
        row_ptr, deg, col, hlin, dinv, b1, out0, actb, N);

    // --- layer 2: 64 -> 64, leaky ---
    mfma_gemm<64, false><<<gemmBlocks, BLK, 0, stream>>>(actb, WT2, dinv, hlin, N);
    agg64_kernel<true><<<aggBlocks, BLK, 0, stream>>>(
        row_ptr, deg, col, hlin, dinv, b2, out1, actb, N);

    // --- layer 3: 64 -> 32, no activation ---
    mfma_gemm<32, false><<<gemmBlocks, BLK, 0, stream>>>(actb, WT3, dinv, hlin, N);
    agg32_kernel<<<aggBlocks, BLK, 0, stream>>>(
        row_ptr, deg, col, hlin, dinv, b3, out2, N);
}

// Round 6
// 277.115 us; speedup vs baseline: 1.5653x; 1.0666x over previous
//
#include <hip/hip_runtime.h>
#include <hip/hip_bf16.h>

typedef __hip_bfloat16 bf16;
typedef __attribute__((ext_vector_type(8))) short bf16x8;
typedef __attribute__((ext_vector_type(4))) short bf16x4;
typedef __attribute__((ext_vector_type(4))) float f32x4;

constexpr int BLK = 256;
constexpr int SCAN2_T = 512;
constexpr int NBLK = 400;      // edge-partition blocks for hist/scatter
// buckets: dst>>8, 256 nodes per bucket. Requires N <= 512*256 = 131072.

__device__ inline float s2f(short s) {
    union { unsigned u; float f; } z;
    z.u = ((unsigned)(unsigned short)s) << 16;
    return z.f;
}
__device__ inline short f2s(float f) {
    union { bf16 h; short s; } u;
    u.h = __float2bfloat16(f);
    return u.s;
}

// --- CSR build via bucketed counting sort (no global atomics) -------------
// Phase A: per-block LDS histogram of dst buckets.
__global__ void bucket_hist(const int* __restrict__ dst, int* __restrict__ blockhist,
                            int E, int EPB, int NB) {
    __shared__ int h[512];
    for (int i = threadIdx.x; i < NB; i += BLK) h[i] = 0;
    __syncthreads();
    int lo = blockIdx.x * EPB;
    int hi = min(E, lo + EPB);
    for (int t = lo + threadIdx.x; t < hi; t += BLK)
        atomicAdd(&h[dst[t] >> 8], 1);
    __syncthreads();
    for (int i = threadIdx.x; i < NB; i += BLK)
        blockhist[i * NBLK + blockIdx.x] = h[i];   // [bucket][blk]
}

// Phase A2: per-bucket exclusive scan over blocks; bucket total out.
__global__ void colscan_kernel(int* __restrict__ blockhist, int* __restrict__ btotal) {
    __shared__ int s[SCAN2_T];
    int b = blockIdx.x;
    int t = threadIdx.x;
    int v = (t < NBLK) ? blockhist[b * NBLK + t] : 0;
    s[t] = v;
    __syncthreads();
    for (int off = 1; off < SCAN2_T; off <<= 1) {
        int add = (t >= off) ? s[t - off] : 0;
        __syncthreads();
        s[t] += add;
        __syncthreads();
    }
    if (t < NBLK) blockhist[b * NBLK + t] = s[t] - v;   // exclusive
    if (t == SCAN2_T - 1) btotal[b] = s[SCAN2_T - 1];   // bucket total
}

// Phase A3 (reused): exclusive scan of bucket totals -> bucket bases (in place).
__global__ void scan2_kernel(int* __restrict__ bsum, int nb) {
    __shared__ int s[SCAN2_T];
    int t = threadIdx.x;
    int v = (t < nb) ? bsum[t] : 0;
    s[t] = v;
    __syncthreads();
    for (int off = 1; off < SCAN2_T; off <<= 1) {
        int add = (t >= off) ? s[t - off] : 0;
        __syncthreads();
        s[t] += add;
        __syncthreads();
    }
    if (t < nb) bsum[t] = s[t] - v;
}

// Phase B: scatter edges into bucket-sorted order via LDS cursors.
__global__ void bucket_scatter(const int* __restrict__ src, const int* __restrict__ dst,
                               const int* __restrict__ blockhist, const int* __restrict__ bbase,
                               int2* __restrict__ ssd, int E, int EPB, int NB) {
    __shared__ int h[512];
    for (int i = threadIdx.x; i < NB; i += BLK)
        h[i] = bbase[i] + blockhist[i * NBLK + blockIdx.x];
    __syncthreads();
    int lo = blockIdx.x * EPB;
    int hi = min(E, lo + EPB);
    for (int t = lo + threadIdx.x; t < hi; t += BLK) {
        int d = dst[t];
        int pos = atomicAdd(&h[d >> 8], 1);    // LDS returning atomic
        int2 e; e.x = src[t]; e.y = d;
        ssd[pos] = e;
    }
}

// Phase C: per-bucket CSR build entirely in LDS; emits col/deg/row_ptr/dinv.
__global__ void bucket_csr(const int2* __restrict__ ssd, const int* __restrict__ bbase,
                           int* __restrict__ col, int* __restrict__ deg,
                           int* __restrict__ row_ptr, float* __restrict__ dinv,
                           int N, int E, int NB) {
    __shared__ int dloc[256];
    __shared__ int ss[256];
    __shared__ int cur[256];
    int b = blockIdx.x;
    int t = threadIdx.x;
    int lo = bbase[b];
    int hi = (b + 1 < NB) ? bbase[b + 1] : E;
    dloc[t] = 0;
    __syncthreads();
    for (int j = lo + t; j < hi; j += BLK)
        atomicAdd(&dloc[ssd[j].y & 255], 1);
    __syncthreads();
    int own = dloc[t];
    ss[t] = own;
    __syncthreads();
    for (int off = 1; off < 256; off <<= 1) {
        int add = (t >= off) ? ss[t - off] : 0;
        __syncthreads();
        ss[t] += add;
        __syncthreads();
    }
    int excl = ss[t] - own;
    cur[t] = lo + excl;
    int node = (b << 8) + t;
    if (node < N) {
        deg[node] = own;
        row_ptr[node] = lo + excl;
        dinv[node] = rsqrtf((float)own + 1.0f);
    }
    __syncthreads();
    for (int j = lo + t; j < hi; j += BLK) {
        int2 e = ssd[j];
        int p = atomicAdd(&cur[e.y & 255], 1);  // LDS returning atomic
        col[p] = e.x;
    }
}

// --- all three weights -> bf16 transposed, one launch ---------------------
__global__ void wconv_all(const float* __restrict__ W1, const float* __restrict__ W2,
                          const float* __restrict__ W3, bf16* __restrict__ WT1,
                          bf16* __restrict__ WT2, bf16* __restrict__ WT3) {
    int idx = blockIdx.x * blockDim.x + threadIdx.x;
    if (idx < 4096) {
        int k = idx >> 6, c = idx & 63;
        WT1[c * 64 + k] = __float2bfloat16(W1[idx]);
    } else if (idx < 8192) {
        int i = idx - 4096, k = i >> 6, c = i & 63;
        WT2[c * 64 + k] = __float2bfloat16(W2[i]);
    } else if (idx < 10240) {
        int i = idx - 8192, k = i >> 5, c = i & 31;
        WT3[c * 64 + k] = __float2bfloat16(W3[i]);
    }
}

// --- MFMA GEMM: hlin[r,c] = bf16( dinv[r] * sum_k in[r,k]*W[k,c] ) --------
// 16x16x32 bf16. Block = 4 waves x 16 rows. C/D: col=lane&15, row=quad*4+reg.
template <int DOUT, bool AF32>
__global__ void mfma_gemm(const void* __restrict__ inv, const bf16* __restrict__ WT,
                          const float* __restrict__ dinv, bf16* __restrict__ hlin, int n) {
    constexpr int NT = DOUT / 16;
    const int lane = threadIdx.x & 63;
    const int wave = threadIdx.x >> 6;
    const int q = lane >> 4;
    const int l16 = lane & 15;
    const int row0 = blockIdx.x * 64 + wave * 16;

    int arow = row0 + l16;
    if (arow >= n) arow = n - 1;

    bf16x8 a0, a1;
    if (AF32) {
        const float* in = (const float*)inv;
        const float* p = in + (size_t)arow * 64 + q * 8;
        float4 f0 = *(const float4*)(p);
        float4 f1 = *(const float4*)(p + 4);
        float4 g0 = *(const float4*)(p + 32);
        float4 g1 = *(const float4*)(p + 36);
        bf16 t0[8] = {__float2bfloat16(f0.x), __float2bfloat16(f0.y), __float2bfloat16(f0.z), __float2bfloat16(f0.w),
                      __float2bfloat16(f1.x), __float2bfloat16(f1.y), __float2bfloat16(f1.z), __float2bfloat16(f1.w)};
        bf16 t1[8] = {__float2bfloat16(g0.x), __float2bfloat16(g0.y), __float2bfloat16(g0.z), __float2bfloat16(g0.w),
                      __float2bfloat16(g1.x), __float2bfloat16(g1.y), __float2bfloat16(g1.z), __float2bfloat16(g1.w)};
        __builtin_memcpy(&a0, t0, 16);
        __builtin_memcpy(&a1, t1, 16);
    } else {
        const bf16* in = (const bf16*)inv;
        a0 = *(const bf16x8*)(in + (size_t)arow * 64 + q * 8);
        a1 = *(const bf16x8*)(in + (size_t)arow * 64 + 32 + q * 8);
    }

    f32x4 acc[NT];
#pragma unroll
    for (int ct = 0; ct < NT; ++ct) {
        const bf16* wrow = WT + (size_t)(ct * 16 + l16) * 64 + q * 8;
        bf16x8 b0 = *(const bf16x8*)(wrow);
        bf16x8 b1 = *(const bf16x8*)(wrow + 32);
        f32x4 c = {0.f, 0.f, 0.f, 0.f};
        c = __builtin_amdgcn_mfma_f32_16x16x32_bf16(a0, b0, c, 0, 0, 0);
        c = __builtin_amdgcn_mfma_f32_16x16x32_bf16(a1, b1, c, 0, 0, 0);
        acc[ct] = c;
    }

    float dv[4];
#pragma unroll
    for (int r = 0; r < 4; ++r) {
        int rr = row0 + q * 4 + r;
        dv[r] = (rr < n) ? dinv[rr] : 0.0f;
    }
#pragma unroll
    for (int ct = 0; ct < NT; ++ct) {
#pragma unroll
        for (int r = 0; r < 4; ++r) {
            int rr = row0 + q * 4 + r;
            if (rr < n)
                hlin[(size_t)rr * DOUT + ct * 16 + l16] = __float2bfloat16(acc[ct][r] * dv[r]);
        }
    }
}

// --- Pull aggregation, 64 feats, 4 nodes per wave, 2-deep pipeline --------
// 16 lanes/node = 8 feature-lanes (fl, dwordx4=8 feats) x 2 edge-groups (g).
// Edge loop unrolled x2 with dual accumulators: 2 hlin gathers + 2 col
// prefetches in flight per wave (2KB+ MLP) to cover L2-miss latency.
// Inactive slots gather the zeroed PAD row (L1-resident) -- branch-free.
template <bool LEAKY>
__global__ void agg64_kernel(const int* __restrict__ row_ptr, const int* __restrict__ deg,
                             const int* __restrict__ col, const bf16* __restrict__ hlin,
                             const float* __restrict__ dinv, const float* __restrict__ b,
                             float* __restrict__ out, bf16* __restrict__ actb, int n) {
    const int wid = (blockIdx.x * blockDim.x + threadIdx.x) >> 6;
    const int lane = threadIdx.x & 63;
    const int sub = lane >> 4;           // node slot 0..3
    const int g = (lane >> 3) & 1;       // edge group 0..1
    const int fl = lane & 7;             // feature block fl*8..+7
    const int node = wid * 4 + sub;
    const int PAD = n;                   // zero row (64-feat layout)

    const bool valid = node < n;
    const int nc = valid ? node : n - 1;
    const int beg = row_ptr[nc];
    const int dg = valid ? deg[nc] : 0;
    const int end = beg + dg;

    float acc[8], acc2[8];
    {   // self loop: g==0 lanes read own row; g==1 lanes read zero PAD row
        int c0 = (valid && g == 0) ? node : PAD;
        bf16x8 sv = *(const bf16x8*)(hlin + (size_t)c0 * 64 + (fl << 3));
#pragma unroll
        for (int k = 0; k < 8; ++k) { acc[k] = s2f(sv[k]); acc2[k] = 0.0f; }
    }

    // shared iteration count: max deg over this wave's 4 nodes
    int m = dg;
    m = max(m, __shfl_xor(m, 16));
    m = max(m, __shfl_xor(m, 32));
    const int iters = (m + 3) >> 2;      // 2 edges/group/iter

    int idx = beg + g;                   // this group's slots: idx, idx+2, ...
    int c0 = col[idx < end ? idx : 0];
    int c1 = col[idx + 2 < end ? idx + 2 : 0];
    for (int j = 0; j < iters; ++j) {
        const int a0 = (idx < end) ? c0 : PAD;
        const int a1 = (idx + 2 < end) ? c1 : PAD;
        idx += 4;
        c0 = col[idx < end ? idx : 0];        // prefetch next pair
        c1 = col[idx + 2 < end ? idx + 2 : 0];
        bf16x8 v0 = *(const bf16x8*)(hlin + (size_t)a0 * 64 + (fl << 3));
        bf16x8 v1 = *(const bf16x8*)(hlin + (size_t)a1 * 64 + (fl << 3));
#pragma unroll
        for (int k = 0; k < 8; ++k) { acc[k] += s2f(v0[k]); acc2[k] += s2f(v1[k]); }
    }

    // merge dual accumulators, then combine the 2 edge groups
#pragma unroll
    for (int k = 0; k < 8; ++k) acc[k] += acc2[k];
#pragma unroll
    for (int k = 0; k < 8; ++k) acc[k] += __shfl_xor(acc[k], 8);

    const float dv = dinv[nc];
    const float4 bb0 = *(const float4*)(b + (fl << 3));
    const float4 bb1 = *(const float4*)(b + (fl << 3) + 4);
    float vals[8];
    vals[0] = acc[0] * dv + bb0.x;
    vals[1] = acc[1] * dv + bb0.y;
    vals[2] = acc[2] * dv + bb0.z;
    vals[3] = acc[3] * dv + bb0.w;
    vals[4] = acc[4] * dv + bb1.x;
    vals[5] = acc[5] * dv + bb1.y;
    vals[6] = acc[6] * dv + bb1.z;
    vals[7] = acc[7] * dv + bb1.w;
    if (LEAKY) {
#pragma unroll
        for (int k = 0; k < 8; ++k) vals[k] = (vals[k] >= 0.0f) ? vals[k] : 0.01f * vals[k];
    }
    if (valid && g == 0) {               // 4 nodes store in parallel: 1KB/wave
        float* op = out + (size_t)node * 64 + (fl << 3);
        f32x4 o0 = {vals[0], vals[1], vals[2], vals[3]};
        f32x4 o1 = {vals[4], vals[5], vals[6], vals[7]};
        __builtin_nontemporal_store(o0, (f32x4*)op);       // out never re-read
        __builtin_nontemporal_store(o1, (f32x4*)(op + 4));
        if (actb) {
            bf16x8 ob;
#pragma unroll
            for (int k = 0; k < 8; ++k) ob[k] = f2s(vals[k]);
            *(bf16x8*)(actb + (size_t)node * 64 + (fl << 3)) = ob;
        }
    }
}

// --- Pull aggregation, 32 feats, 4 nodes per wave, 2-deep pipeline --------
// Same structure with dwordx2 gathers (fl covers 4 feats). PAD row = 2n
// (32-feat layout) aliases the same zeroed halfword region as agg64's PAD.
__global__ void agg32_kernel(const int* __restrict__ row_ptr, const int* __restrict__ deg,
                             const int* __restrict__ col, const bf16* __restrict__ hlin,
                             const float* __restrict__ dinv, const float* __restrict__ b,
                             float* __restrict__ out, int n) {
    const int wid = (blockIdx.x * blockDim.x + threadIdx.x) >> 6;
    const int lane = threadIdx.x & 63;
    const int sub = lane >> 4;
    const int g = (lane >> 3) & 1;
    const int fl = lane & 7;             // feature block fl*4..+3
    const int node = wid * 4 + sub;
    const int PAD = 2 * n;               // zero row (32-feat layout)

    const bool valid = node < n;
    const int nc = valid ? node : n - 1;
    const int beg = row_ptr[nc];
    const int dg = valid ? deg[nc] : 0;
    const int end = beg + dg;

    float acc[4], acc2[4];
    {
        int c0 = (valid && g == 0) ? node : PAD;
        bf16x4 sv = *(const bf16x4*)(hlin + (size_t)c0 * 32 + (fl << 2));
#pragma unroll
        for (int k = 0; k < 4; ++k) { acc[k] = s2f(sv[k]); acc2[k] = 0.0f; }
    }

    int m = dg;
    m = max(m, __shfl_xor(m, 16));
    m = max(m, __shfl_xor(m, 32));
    const int iters = (m + 3) >> 2;

    int idx = beg + g;
    int c0 = col[idx < end ? idx : 0];
    int c1 = col[idx + 2 < end ? idx + 2 : 0];
    for (int j = 0; j < iters; ++j) {
        const int a0 = (idx < end) ? c0 : PAD;
        const int a1 = (idx + 2 < end) ? c1 : PAD;
        idx += 4;
        c0 = col[idx < end ? idx : 0];
        c1 = col[idx + 2 < end ? idx + 2 : 0];
        bf16x4 v0 = *(const bf16x4*)(hlin + (size_t)a0 * 32 + (fl << 2));
        bf16x4 v1 = *(const bf16x4*)(hlin + (size_t)a1 * 32 + (fl << 2));
#pragma unroll
        for (int k = 0; k < 4; ++k) { acc[k] += s2f(v0[k]); acc2[k] += s2f(v1[k]); }
    }

#pragma unroll
    for (int k = 0; k < 4; ++k) acc[k] += acc2[k];
#pragma unroll
    for (int k = 0; k < 4; ++k) acc[k] += __shfl_xor(acc[k], 8);

    const float dv = dinv[nc];
    const float4 bb = *(const float4*)(b + (fl << 2));
    float vals[4];
    vals[0] = acc[0] * dv + bb.x;
    vals[1] = acc[1] * dv + bb.y;
    vals[2] = acc[2] * dv + bb.z;
    vals[3] = acc[3] * dv + bb.w;
    if (valid && g == 0) {               // 4 x 128B contiguous per wave
        f32x4 o = {vals[0], vals[1], vals[2], vals[3]};
        __builtin_nontemporal_store(o, (f32x4*)(out + (size_t)node * 32 + (fl << 2)));
    }
}

extern "C" void kernel_launch(void* const* d_in, const int* in_sizes, int n_in,
                              void* d_out, int out_size, void* d_ws, size_t ws_size,
                              hipStream_t stream) {
    const float* x  = (const float*)d_in[0];
    const int*   ei = (const int*)d_in[1];
    const float* W1 = (const float*)d_in[2];
    const float* b1 = (const float*)d_in[3];
    const float* W2 = (const float*)d_in[4];
    const float* b2 = (const float*)d_in[5];
    const float* W3 = (const float*)d_in[6];
    const float* b3 = (const float*)d_in[7];
    float* out = (float*)d_out;

    const int N = in_sizes[0] / 64;   // 100000
    const int E = in_sizes[1] / 2;    // 1600000
    const int* src = ei;
    const int* dst = ei + E;

    const int NB  = (N + 255) >> 8;           // buckets (<=512 for N<=131072)
    const int EPB = (E + NBLK - 1) / NBLK;    // edges per partition block

    char* w = (char*)d_ws;
    auto take = [&](size_t bytes) { char* p = w; w += (bytes + 15) & ~(size_t)15; return p; };
    int*   col       = (int*)take((size_t)E * 4);
    int2*  ssd       = (int2*)take((size_t)E * 8);
    bf16*  hlin      = (bf16*)take(((size_t)N * 64 + 64) * 2);  // +64 halfwords: PAD row
    bf16*  actb      = (bf16*)take((size_t)N * 64 * 2);
    bf16*  WT1       = (bf16*)take(64 * 64 * 2);
    bf16*  WT2       = (bf16*)take(64 * 64 * 2);
    bf16*  WT3       = (bf16*)take(32 * 64 * 2);
    int*   deg       = (int*)take((size_t)N * 4);
    int*   row_ptr   = (int*)take((size_t)N * 4);
    float* dinv      = (float*)take((size_t)N * 4);
    int*   blockhist = (int*)take((size_t)NB * NBLK * 4);
    int*   btotal    = (int*)take((size_t)SCAN2_T * 4);

    float* out0 = out;
    float* out1 = out + (size_t)N * 64;
    float* out2 = out + (size_t)N * 128;

    const int gemmBlocks = (N + 63) / 64;
    const int aggWaves = (N + 3) / 4;
    const int aggBlocks = (aggWaves * 64 + BLK - 1) / BLK;

    // zero the PAD row: halfwords [64N, 64N+64) -- covers agg64 PAD=N
    // (reads [64N,64N+64)) and agg32 PAD=2N (reads [64N,64N+32)); this
    // region is never written by any gemm (they write < 64N halfwords).
    hipMemsetAsync(hlin + (size_t)N * 64, 0, 128, stream);

    // --- CSR build: bucketed counting sort, LDS atomics only ---
    bucket_hist<<<NBLK, BLK, 0, stream>>>(dst, blockhist, E, EPB, NB);
    colscan_kernel<<<NB, SCAN2_T, 0, stream>>>(blockhist, btotal);
    scan2_kernel<<<1, SCAN2_T, 0, stream>>>(btotal, NB);       // -> bucket bases
    bucket_scatter<<<NBLK, BLK, 0, stream>>>(src, dst, blockhist, btotal, ssd, E, EPB, NB);
    bucket_csr<<<NB, BLK, 0, stream>>>(ssd, btotal, col, deg, row_ptr, dinv, N, E, NB);

    // --- weights -> bf16 transposed ---
    wconv_all<<<40, BLK, 0, stream>>>(W1, W2, W3, WT1, WT2, WT3);

    // --- layer 1: 64 -> 64, leaky ---
    mfma_gemm<64, true><<<gemmBlocks, BLK, 0, stream>>>(x, WT1, dinv, hlin, N);
    agg64_kernel<true><<<aggBlocks, BLK, 0, stream>>>(
        row_ptr, deg, col, hlin, dinv, b1, out0, actb, N);

    // --- layer 2: 64 -> 64, leaky ---
    mfma_gemm<64, false><<<gemmBlocks, BLK, 0, stream>>>(actb, WT2, dinv, hlin, N);
    agg64_kernel<true><<<aggBlocks, BLK, 0, stream>>>(
        row_ptr, deg, col, hlin, dinv, b2, out1, actb, N);

    // --- layer 3: 64 -> 32, no activation ---
    mfma_gemm<32, false><<<gemmBlocks, BLK, 0, stream>>>(actb, WT3, dinv, hlin, N);
    agg32_kernel<<<aggBlocks, BLK, 0, stream>>>(
        row_ptr, deg, col, hlin, dinv, b3, out2, N);
}

// Round 7
// 269.816 us; speedup vs baseline: 1.6077x; 1.0271x over previous
//
#include <hip/hip_runtime.h>
#include <hip/hip_bf16.h>

typedef __hip_bfloat16 bf16;
typedef __attribute__((ext_vector_type(8))) short bf16x8;
typedef __attribute__((ext_vector_type(4))) short bf16x4;
typedef __attribute__((ext_vector_type(4))) float f32x4;

constexpr int BLK = 256;
constexpr int SCAN2_T = 512;
constexpr int NBLK = 400;      // edge-partition blocks for hist/scatter
// buckets: dst>>8, 256 nodes per bucket. Requires N <= 512*256 = 131072.
// packed ssd entry: (src<<8)|(dst&255) -- needs N <= 2^17 (src fits 17 bits).

__device__ inline float s2f(short s) {
    union { unsigned u; float f; } z;
    z.u = ((unsigned)(unsigned short)s) << 16;
    return z.f;
}
__device__ inline short f2s(float f) {
    union { bf16 h; short s; } u;
    u.h = __float2bfloat16(f);
    return u.s;
}

// --- CSR build via bucketed counting sort (no global atomics) -------------
// Phase A: per-block LDS histogram of dst buckets.
__global__ void bucket_hist(const int* __restrict__ dst, int* __restrict__ blockhist,
                            int E, int EPB, int NB) {
    __shared__ int h[512];
    for (int i = threadIdx.x; i < NB; i += BLK) h[i] = 0;
    __syncthreads();
    int lo = blockIdx.x * EPB;
    int hi = min(E, lo + EPB);
    for (int t = lo + threadIdx.x; t < hi; t += BLK)
        atomicAdd(&h[dst[t] >> 8], 1);
    __syncthreads();
    for (int i = threadIdx.x; i < NB; i += BLK)
        blockhist[i * NBLK + blockIdx.x] = h[i];   // [bucket][blk]
}

// Phase A2: per-bucket exclusive scan over blocks; bucket total out.
__global__ void colscan_kernel(int* __restrict__ blockhist, int* __restrict__ btotal) {
    __shared__ int s[SCAN2_T];
    int b = blockIdx.x;
    int t = threadIdx.x;
    int v = (t < NBLK) ? blockhist[b * NBLK + t] : 0;
    s[t] = v;
    __syncthreads();
    for (int off = 1; off < SCAN2_T; off <<= 1) {
        int add = (t >= off) ? s[t - off] : 0;
        __syncthreads();
        s[t] += add;
        __syncthreads();
    }
    if (t < NBLK) blockhist[b * NBLK + t] = s[t] - v;   // exclusive
    if (t == SCAN2_T - 1) btotal[b] = s[SCAN2_T - 1];   // bucket total
}

// Phase A3 (reused): exclusive scan of bucket totals -> bucket bases (in place).
__global__ void scan2_kernel(int* __restrict__ bsum, int nb) {
    __shared__ int s[SCAN2_T];
    int t = threadIdx.x;
    int v = (t < nb) ? bsum[t] : 0;
    s[t] = v;
    __syncthreads();
    for (int off = 1; off < SCAN2_T; off <<= 1) {
        int add = (t >= off) ? s[t - off] : 0;
        __syncthreads();
        s[t] += add;
        __syncthreads();
    }
    if (t < nb) bsum[t] = s[t] - v;
}

// Phase B: scatter edges into bucket-sorted order via LDS cursors.
// Packed entry: (src<<8)|(dst&255) -- 4B/edge instead of 8B.
__global__ void bucket_scatter(const int* __restrict__ src, const int* __restrict__ dst,
                               const int* __restrict__ blockhist, const int* __restrict__ bbase,
                               int* __restrict__ ssd, int E, int EPB, int NB) {
    __shared__ int h[512];
    for (int i = threadIdx.x; i < NB; i += BLK)
        h[i] = bbase[i] + blockhist[i * NBLK + blockIdx.x];
    __syncthreads();
    int lo = blockIdx.x * EPB;
    int hi = min(E, lo + EPB);
    for (int t = lo + threadIdx.x; t < hi; t += BLK) {
        int d = dst[t];
        int pos = atomicAdd(&h[d >> 8], 1);    // LDS returning atomic
        ssd[pos] = (src[t] << 8) | (d & 255);
    }
}

// Phase C: per-bucket CSR build entirely in LDS; emits col/deg/row_ptr/dinv.
__global__ void bucket_csr(const int* __restrict__ ssd, const int* __restrict__ bbase,
                           int* __restrict__ col, int* __restrict__ deg,
                           int* __restrict__ row_ptr, float* __restrict__ dinv,
                           int N, int E, int NB) {
    __shared__ int dloc[256];
    __shared__ int ss[256];
    __shared__ int cur[256];
    int b = blockIdx.x;
    int t = threadIdx.x;
    int lo = bbase[b];
    int hi = (b + 1 < NB) ? bbase[b + 1] : E;
    dloc[t] = 0;
    __syncthreads();
    for (int j = lo + t; j < hi; j += BLK)
        atomicAdd(&dloc[ssd[j] & 255], 1);
    __syncthreads();
    int own = dloc[t];
    ss[t] = own;
    __syncthreads();
    for (int off = 1; off < 256; off <<= 1) {
        int add = (t >= off) ? ss[t - off] : 0;
        __syncthreads();
        ss[t] += add;
        __syncthreads();
    }
    int excl = ss[t] - own;
    cur[t] = lo + excl;
    int node = (b << 8) + t;
    if (node < N) {
        deg[node] = own;
        row_ptr[node] = lo + excl;
        dinv[node] = rsqrtf((float)own + 1.0f);
    }
    __syncthreads();
    for (int j = lo + t; j < hi; j += BLK) {
        unsigned e = (unsigned)ssd[j];
        int p = atomicAdd(&cur[e & 255], 1);  // LDS returning atomic
        col[p] = (int)(e >> 8);
    }
}

// --- all three weights -> bf16 transposed, one launch ---------------------
__global__ void wconv_all(const float* __restrict__ W1, const float* __restrict__ W2,
                          const float* __restrict__ W3, bf16* __restrict__ WT1,
                          bf16* __restrict__ WT2, bf16* __restrict__ WT3) {
    int idx = blockIdx.x * blockDim.x + threadIdx.x;
    if (idx < 4096) {
        int k = idx >> 6, c = idx & 63;
        WT1[c * 64 + k] = __float2bfloat16(W1[idx]);
    } else if (idx < 8192) {
        int i = idx - 4096, k = i >> 6, c = i & 63;
        WT2[c * 64 + k] = __float2bfloat16(W2[i]);
    } else if (idx < 10240) {
        int i = idx - 8192, k = i >> 5, c = i & 31;
        WT3[c * 64 + k] = __float2bfloat16(W3[i]);
    }
}

// --- MFMA GEMM: hlin[r,c] = bf16( dinv[r] * sum_k in[r,k]*W[k,c] ) --------
// 16x16x32 bf16. Block = 4 waves x 16 rows. C/D: col=lane&15, row=quad*4+reg.
template <int DOUT, bool AF32>
__global__ void mfma_gemm(const void* __restrict__ inv, const bf16* __restrict__ WT,
                          const float* __restrict__ dinv, bf16* __restrict__ hlin, int n) {
    constexpr int NT = DOUT / 16;
    const int lane = threadIdx.x & 63;
    const int wave = threadIdx.x >> 6;
    const int q = lane >> 4;
    const int l16 = lane & 15;
    const int row0 = blockIdx.x * 64 + wave * 16;

    int arow = row0 + l16;
    if (arow >= n) arow = n - 1;

    bf16x8 a0, a1;
    if (AF32) {
        const float* in = (const float*)inv;
        const float* p = in + (size_t)arow * 64 + q * 8;
        float4 f0 = *(const float4*)(p);
        float4 f1 = *(const float4*)(p + 4);
        float4 g0 = *(const float4*)(p + 32);
        float4 g1 = *(const float4*)(p + 36);
        bf16 t0[8] = {__float2bfloat16(f0.x), __float2bfloat16(f0.y), __float2bfloat16(f0.z), __float2bfloat16(f0.w),
                      __float2bfloat16(f1.x), __float2bfloat16(f1.y), __float2bfloat16(f1.z), __float2bfloat16(f1.w)};
        bf16 t1[8] = {__float2bfloat16(g0.x), __float2bfloat16(g0.y), __float2bfloat16(g0.z), __float2bfloat16(g0.w),
                      __float2bfloat16(g1.x), __float2bfloat16(g1.y), __float2bfloat16(g1.z), __float2bfloat16(g1.w)};
        __builtin_memcpy(&a0, t0, 16);
        __builtin_memcpy(&a1, t1, 16);
    } else {
        const bf16* in = (const bf16*)inv;
        a0 = *(const bf16x8*)(in + (size_t)arow * 64 + q * 8);
        a1 = *(const bf16x8*)(in + (size_t)arow * 64 + 32 + q * 8);
    }

    f32x4 acc[NT];
#pragma unroll
    for (int ct = 0; ct < NT; ++ct) {
        const bf16* wrow = WT + (size_t)(ct * 16 + l16) * 64 + q * 8;
        bf16x8 b0 = *(const bf16x8*)(wrow);
        bf16x8 b1 = *(const bf16x8*)(wrow + 32);
        f32x4 c = {0.f, 0.f, 0.f, 0.f};
        c = __builtin_amdgcn_mfma_f32_16x16x32_bf16(a0, b0, c, 0, 0, 0);
        c = __builtin_amdgcn_mfma_f32_16x16x32_bf16(a1, b1, c, 0, 0, 0);
        acc[ct] = c;
    }

    float dv[4];
#pragma unroll
    for (int r = 0; r < 4; ++r) {
        int rr = row0 + q * 4 + r;
        dv[r] = (rr < n) ? dinv[rr] : 0.0f;
    }
#pragma unroll
    for (int ct = 0; ct < NT; ++ct) {
#pragma unroll
        for (int r = 0; r < 4; ++r) {
            int rr = row0 + q * 4 + r;
            if (rr < n)
                hlin[(size_t)rr * DOUT + ct * 16 + l16] = __float2bfloat16(acc[ct][r] * dv[r]);
        }
    }
}

// --- Pull aggregation, 64 feats, 4 nodes per wave, 4-deep pipeline --------
// 16 lanes/node = 8 feature-lanes (fl, dwordx4=8 feats) x 2 edge-groups (g).
// Edge loop unrolled x4 with dual accumulators: 4 hlin gathers + 4 col
// prefetches in flight per wave (4KB+ MLP) to cover L2/L3-miss latency.
// Inactive slots gather the zeroed PAD row (L1-resident) -- branch-free.
// __launch_bounds__(256,8): cap VGPR at 64 so 8 waves/SIMD stay available.
template <bool LEAKY>
__global__ __launch_bounds__(256, 8)
void agg64_kernel(const int* __restrict__ row_ptr, const int* __restrict__ deg,
                  const int* __restrict__ col, const bf16* __restrict__ hlin,
                  const float* __restrict__ dinv, const float* __restrict__ b,
                  float* __restrict__ out, bf16* __restrict__ actb, int n) {
    const int wid = (blockIdx.x * blockDim.x + threadIdx.x) >> 6;
    const int lane = threadIdx.x & 63;
    const int sub = lane >> 4;           // node slot 0..3
    const int g = (lane >> 3) & 1;       // edge group 0..1
    const int fl = lane & 7;             // feature block fl*8..+7
    const int node = wid * 4 + sub;
    const int PAD = n;                   // zero row (64-feat layout)

    const bool valid = node < n;
    const int nc = valid ? node : n - 1;
    const int beg = row_ptr[nc];
    const int dg = valid ? deg[nc] : 0;
    const int end = beg + dg;

    float acc[8], acc2[8];
    {   // self loop: g==0 lanes read own row; g==1 lanes read zero PAD row
        int c0 = (valid && g == 0) ? node : PAD;
        bf16x8 sv = *(const bf16x8*)(hlin + (size_t)c0 * 64 + (fl << 3));
#pragma unroll
        for (int k = 0; k < 8; ++k) { acc[k] = s2f(sv[k]); acc2[k] = 0.0f; }
    }

    // shared iteration count: max deg over this wave's 4 nodes
    int m = dg;
    m = max(m, __shfl_xor(m, 16));
    m = max(m, __shfl_xor(m, 32));
    const int iters = (m + 7) >> 3;      // 4 edges/group/iter

    int idx = beg + g;                   // this group's slots: idx, idx+2, ...
    int c0 = col[idx     < end ? idx     : 0];
    int c1 = col[idx + 2 < end ? idx + 2 : 0];
    int c2 = col[idx + 4 < end ? idx + 4 : 0];
    int c3 = col[idx + 6 < end ? idx + 6 : 0];
    for (int j = 0; j < iters; ++j) {
        const int a0 = (idx     < end) ? c0 : PAD;
        const int a1 = (idx + 2 < end) ? c1 : PAD;
        const int a2 = (idx + 4 < end) ? c2 : PAD;
        const int a3 = (idx + 6 < end) ? c3 : PAD;
        idx += 8;
        c0 = col[idx     < end ? idx     : 0];   // prefetch next quad
        c1 = col[idx + 2 < end ? idx + 2 : 0];
        c2 = col[idx + 4 < end ? idx + 4 : 0];
        c3 = col[idx + 6 < end ? idx + 6 : 0];
        bf16x8 v0 = *(const bf16x8*)(hlin + (size_t)a0 * 64 + (fl << 3));
        bf16x8 v1 = *(const bf16x8*)(hlin + (size_t)a1 * 64 + (fl << 3));
        bf16x8 v2 = *(const bf16x8*)(hlin + (size_t)a2 * 64 + (fl << 3));
        bf16x8 v3 = *(const bf16x8*)(hlin + (size_t)a3 * 64 + (fl << 3));
#pragma unroll
        for (int k = 0; k < 8; ++k) {
            acc[k]  += s2f(v0[k]) + s2f(v1[k]);
            acc2[k] += s2f(v2[k]) + s2f(v3[k]);
        }
    }

    // merge dual accumulators, then combine the 2 edge groups
#pragma unroll
    for (int k = 0; k < 8; ++k) acc[k] += acc2[k];
#pragma unroll
    for (int k = 0; k < 8; ++k) acc[k] += __shfl_xor(acc[k], 8);

    const float dv = dinv[nc];
    const float4 bb0 = *(const float4*)(b + (fl << 3));
    const float4 bb1 = *(const float4*)(b + (fl << 3) + 4);
    float vals[8];
    vals[0] = acc[0] * dv + bb0.x;
    vals[1] = acc[1] * dv + bb0.y;
    vals[2] = acc[2] * dv + bb0.z;
    vals[3] = acc[3] * dv + bb0.w;
    vals[4] = acc[4] * dv + bb1.x;
    vals[5] = acc[5] * dv + bb1.y;
    vals[6] = acc[6] * dv + bb1.z;
    vals[7] = acc[7] * dv + bb1.w;
    if (LEAKY) {
#pragma unroll
        for (int k = 0; k < 8; ++k) vals[k] = (vals[k] >= 0.0f) ? vals[k] : 0.01f * vals[k];
    }
    if (valid && g == 0) {               // 4 nodes store in parallel: 1KB/wave
        float* op = out + (size_t)node * 64 + (fl << 3);
        f32x4 o0 = {vals[0], vals[1], vals[2], vals[3]};
        f32x4 o1 = {vals[4], vals[5], vals[6], vals[7]};
        __builtin_nontemporal_store(o0, (f32x4*)op);       // out never re-read
        __builtin_nontemporal_store(o1, (f32x4*)(op + 4));
        if (actb) {
            bf16x8 ob;
#pragma unroll
            for (int k = 0; k < 8; ++k) ob[k] = f2s(vals[k]);
            *(bf16x8*)(actb + (size_t)node * 64 + (fl << 3)) = ob;
        }
    }
}

// --- Pull aggregation, 32 feats, 4 nodes per wave, 4-deep pipeline --------
// Same structure with dwordx2 gathers (fl covers 4 feats). PAD row = 2n
// (32-feat layout) aliases the same zeroed halfword region as agg64's PAD.
__global__ __launch_bounds__(256, 8)
void agg32_kernel(const int* __restrict__ row_ptr, const int* __restrict__ deg,
                  const int* __restrict__ col, const bf16* __restrict__ hlin,
                  const float* __restrict__ dinv, const float* __restrict__ b,
                  float* __restrict__ out, int n) {
    const int wid = (blockIdx.x * blockDim.x + threadIdx.x) >> 6;
    const int lane = threadIdx.x & 63;
    const int sub = lane >> 4;
    const int g = (lane >> 3) & 1;
    const int fl = lane & 7;             // feature block fl*4..+3
    const int node = wid * 4 + sub;
    const int PAD = 2 * n;               // zero row (32-feat layout)

    const bool valid = node < n;
    const int nc = valid ? node : n - 1;
    const int beg = row_ptr[nc];
    const int dg = valid ? deg[nc] : 0;
    const int end = beg + dg;

    float acc[4], acc2[4];
    {
        int c0 = (valid && g == 0) ? node : PAD;
        bf16x4 sv = *(const bf16x4*)(hlin + (size_t)c0 * 32 + (fl << 2));
#pragma unroll
        for (int k = 0; k < 4; ++k) { acc[k] = s2f(sv[k]); acc2[k] = 0.0f; }
    }

    int m = dg;
    m = max(m, __shfl_xor(m, 16));
    m = max(m, __shfl_xor(m, 32));
    const int iters = (m + 7) >> 3;

    int idx = beg + g;
    int c0 = col[idx     < end ? idx     : 0];
    int c1 = col[idx + 2 < end ? idx + 2 : 0];
    int c2 = col[idx + 4 < end ? idx + 4 : 0];
    int c3 = col[idx + 6 < end ? idx + 6 : 0];
    for (int j = 0; j < iters; ++j) {
        const int a0 = (idx     < end) ? c0 : PAD;
        const int a1 = (idx + 2 < end) ? c1 : PAD;
        const int a2 = (idx + 4 < end) ? c2 : PAD;
        const int a3 = (idx + 6 < end) ? c3 : PAD;
        idx += 8;
        c0 = col[idx     < end ? idx     : 0];
        c1 = col[idx + 2 < end ? idx + 2 : 0];
        c2 = col[idx + 4 < end ? idx + 4 : 0];
        c3 = col[idx + 6 < end ? idx + 6 : 0];
        bf16x4 v0 = *(const bf16x4*)(hlin + (size_t)a0 * 32 + (fl << 2));
        bf16x4 v1 = *(const bf16x4*)(hlin + (size_t)a1 * 32 + (fl << 2));
        bf16x4 v2 = *(const bf16x4*)(hlin + (size_t)a2 * 32 + (fl << 2));
        bf16x4 v3 = *(const bf16x4*)(hlin + (size_t)a3 * 32 + (fl << 2));
#pragma unroll
        for (int k = 0; k < 4; ++k) {
            acc[k]  += s2f(v0[k]) + s2f(v1[k]);
            acc2[k] += s2f(v2[k]) + s2f(v3[k]);
        }
    }

#pragma unroll
    for (int k = 0; k < 4; ++k) acc[k] += acc2[k];
#pragma unroll
    for (int k = 0; k < 4; ++k) acc[k] += __shfl_xor(acc[k], 8);

    const float dv = dinv[nc];
    const float4 bb = *(const float4*)(b + (fl << 2));
    float vals[4];
    vals[0] = acc[0] * dv + bb.x;
    vals[1] = acc[1] * dv + bb.y;
    vals[2] = acc[2] * dv + bb.z;
    vals[3] = acc[3] * dv + bb.w;
    if (valid && g == 0) {               // 4 x 128B contiguous per wave
        f32x4 o = {vals[0], vals[1], vals[2], vals[3]};
        __builtin_nontemporal_store(o, (f32x4*)(out + (size_t)node * 32 + (fl << 2)));
    }
}

extern "C" void kernel_launch(void* const* d_in, const int* in_sizes, int n_in,
                              void* d_out, int out_size, void* d_ws, size_t ws_size,
                              hipStream_t stream) {
    const float* x  = (const float*)d_in[0];
    const int*   ei = (const int*)d_in[1];
    const float* W1 = (const float*)d_in[2];
    const float* b1 = (const float*)d_in[3];
    const float* W2 = (const float*)d_in[4];
    const float* b2 = (const float*)d_in[5];
    const float* W3 = (const float*)d_in[6];
    const float* b3 = (const float*)d_in[7];
    float* out = (float*)d_out;

    const int N = in_sizes[0] / 64;   // 100000
    const int E = in_sizes[1] / 2;    // 1600000
    const int* src = ei;
    const int* dst = ei + E;

    const int NB  = (N + 255) >> 8;           // buckets (<=512 for N<=131072)
    const int EPB = (E + NBLK - 1) / NBLK;    // edges per partition block

    char* w = (char*)d_ws;
    auto take = [&](size_t bytes) { char* p = w; w += (bytes + 15) & ~(size_t)15; return p; };
    int*   col       = (int*)take((size_t)E * 4);
    int*   ssd       = (int*)take((size_t)E * 4);   // packed (src<<8)|(dst&255)
    bf16*  hlin      = (bf16*)take(((size_t)N * 64 + 64) * 2);  // +64 halfwords: PAD row
    bf16*  actb      = (bf16*)take((size_t)N * 64 * 2);
    bf16*  WT1       = (bf16*)take(64 * 64 * 2);
    bf16*  WT2       = (bf16*)take(64 * 64 * 2);
    bf16*  WT3       = (bf16*)take(32 * 64 * 2);
    int*   deg       = (int*)take((size_t)N * 4);
    int*   row_ptr   = (int*)take((size_t)N * 4);
    float* dinv      = (float*)take((size_t)N * 4);
    int*   blockhist = (int*)take((size_t)NB * NBLK * 4);
    int*   btotal    = (int*)take((size_t)SCAN2_T * 4);

    float* out0 = out;
    float* out1 = out + (size_t)N * 64;
    float* out2 = out + (size_t)N * 128;

    const int gemmBlocks = (N + 63) / 64;
    const int aggWaves = (N + 3) / 4;
    const int aggBlocks = (aggWaves * 64 + BLK - 1) / BLK;

    // zero the PAD row: halfwords [64N, 64N+64) -- covers agg64 PAD=N
    // (reads [64N,64N+64)) and agg32 PAD=2N (reads [64N,64N+32)); this
    // region is never written by any gemm (they write < 64N halfwords).
    hipMemsetAsync(hlin + (size_t)N * 64, 0, 128, stream);

    // --- CSR build: bucketed counting sort, LDS atomics only ---
    bucket_hist<<<NBLK, BLK, 0, stream>>>(dst, blockhist, E, EPB, NB);
    colscan_kernel<<<NB, SCAN2_T, 0, stream>>>(blockhist, btotal);
    scan2_kernel<<<1, SCAN2_T, 0, stream>>>(btotal, NB);       // -> bucket bases
    bucket_scatter<<<NBLK, BLK, 0, stream>>>(src, dst, blockhist, btotal, ssd, E, EPB, NB);
    bucket_csr<<<NB, BLK, 0, stream>>>(ssd, btotal, col, deg, row_ptr, dinv, N, E, NB);

    // --- weights -> bf16 transposed ---
    wconv_all<<<40, BLK, 0, stream>>>(W1, W2, W3, WT1, WT2, WT3);

    // --- layer 1: 64 -> 64, leaky ---
    mfma_gemm<64, true><<<gemmBlocks, BLK, 0, stream>>>(x, WT1, dinv, hlin, N);
    agg64_kernel<true><<<aggBlocks, BLK, 0, stream>>>(
        row_ptr, deg, col, hlin, dinv, b1, out0, actb, N);

    // --- layer 2: 64 -> 64, leaky ---
    mfma_gemm<64, false><<<gemmBlocks, BLK, 0, stream>>>(actb, WT2, dinv, hlin, N);
    agg64_kernel<true><<<aggBlocks, BLK, 0, stream>>>(
        row_ptr, deg, col, hlin, dinv, b2, out1, actb, N);

    // --- layer 3: 64 -> 32, no activation ---
    mfma_gemm<32, false><<<gemmBlocks, BLK, 0, stream>>>(actb, WT3, dinv, hlin, N);
    agg32_kernel<<<aggBlocks, BLK, 0, stream>>>(
        row_ptr, deg, col, hlin, dinv, b3, out2, N);
}

// Round 8
// 260.864 us; speedup vs baseline: 1.6628x; 1.0343x over previous
//
#include <hip/hip_runtime.h>
#include <hip/hip_bf16.h>

typedef __hip_bfloat16 bf16;
typedef __attribute__((ext_vector_type(8))) short bf16x8;
typedef __attribute__((ext_vector_type(4))) short bf16x4;
typedef __attribute__((ext_vector_type(4))) float f32x4;

constexpr int BLK = 256;
constexpr int SCAN2_T = 512;
constexpr int NBLK = 400;      // edge-partition blocks for hist/scatter
// buckets: dst>>8, 256 nodes per bucket. Requires N <= 512*256 = 131072.
// packed ssd entry: (src<<8)|(dst&255) -- needs N <= 2^17 (src fits 17 bits).

__device__ inline float s2f(short s) {
    union { unsigned u; float f; } z;
    z.u = ((unsigned)(unsigned short)s) << 16;
    return z.f;
}
__device__ inline short f2s(float f) {
    union { bf16 h; short s; } u;
    u.h = __float2bfloat16(f);
    return u.s;
}

// --- CSR build via bucketed counting sort (no global atomics) -------------
__global__ void bucket_hist(const int* __restrict__ dst, int* __restrict__ blockhist,
                            int E, int EPB, int NB) {
    __shared__ int h[512];
    for (int i = threadIdx.x; i < NB; i += BLK) h[i] = 0;
    __syncthreads();
    int lo = blockIdx.x * EPB;
    int hi = min(E, lo + EPB);
    for (int t = lo + threadIdx.x; t < hi; t += BLK)
        atomicAdd(&h[dst[t] >> 8], 1);
    __syncthreads();
    for (int i = threadIdx.x; i < NB; i += BLK)
        blockhist[i * NBLK + blockIdx.x] = h[i];   // [bucket][blk]
}

__global__ void colscan_kernel(int* __restrict__ blockhist, int* __restrict__ btotal) {
    __shared__ int s[SCAN2_T];
    int b = blockIdx.x;
    int t = threadIdx.x;
    int v = (t < NBLK) ? blockhist[b * NBLK + t] : 0;
    s[t] = v;
    __syncthreads();
    for (int off = 1; off < SCAN2_T; off <<= 1) {
        int add = (t >= off) ? s[t - off] : 0;
        __syncthreads();
        s[t] += add;
        __syncthreads();
    }
    if (t < NBLK) blockhist[b * NBLK + t] = s[t] - v;   // exclusive
    if (t == SCAN2_T - 1) btotal[b] = s[SCAN2_T - 1];   // bucket total
}

__global__ void scan2_kernel(int* __restrict__ bsum, int nb) {
    __shared__ int s[SCAN2_T];
    int t = threadIdx.x;
    int v = (t < nb) ? bsum[t] : 0;
    s[t] = v;
    __syncthreads();
    for (int off = 1; off < SCAN2_T; off <<= 1) {
        int add = (t >= off) ? s[t - off] : 0;
        __syncthreads();
        s[t] += add;
        __syncthreads();
    }
    if (t < nb) bsum[t] = s[t] - v;
}

// Packed entry: (src<<8)|(dst&255) -- 4B/edge.
__global__ void bucket_scatter(const int* __restrict__ src, const int* __restrict__ dst,
                               const int* __restrict__ blockhist, const int* __restrict__ bbase,
                               int* __restrict__ ssd, int E, int EPB, int NB) {
    __shared__ int h[512];
    for (int i = threadIdx.x; i < NB; i += BLK)
        h[i] = bbase[i] + blockhist[i * NBLK + blockIdx.x];
    __syncthreads();
    int lo = blockIdx.x * EPB;
    int hi = min(E, lo + EPB);
    for (int t = lo + threadIdx.x; t < hi; t += BLK) {
        int d = dst[t];
        int pos = atomicAdd(&h[d >> 8], 1);    // LDS returning atomic
        ssd[pos] = (src[t] << 8) | (d & 255);
    }
}

__global__ void bucket_csr(const int* __restrict__ ssd, const int* __restrict__ bbase,
                           int* __restrict__ col, int* __restrict__ deg,
                           int* __restrict__ row_ptr, float* __restrict__ dinv,
                           int N, int E, int NB) {
    __shared__ int dloc[256];
    __shared__ int ss[256];
    __shared__ int cur[256];
    int b = blockIdx.x;
    int t = threadIdx.x;
    int lo = bbase[b];
    int hi = (b + 1 < NB) ? bbase[b + 1] : E;
    dloc[t] = 0;
    __syncthreads();
    for (int j = lo + t; j < hi; j += BLK)
        atomicAdd(&dloc[ssd[j] & 255], 1);
    __syncthreads();
    int own = dloc[t];
    ss[t] = own;
    __syncthreads();
    for (int off = 1; off < 256; off <<= 1) {
        int add = (t >= off) ? ss[t - off] : 0;
        __syncthreads();
        ss[t] += add;
        __syncthreads();
    }
    int excl = ss[t] - own;
    cur[t] = lo + excl;
    int node = (b << 8) + t;
    if (node < N) {
        deg[node] = own;
        row_ptr[node] = lo + excl;
        dinv[node] = rsqrtf((float)own + 1.0f);
    }
    __syncthreads();
    for (int j = lo + t; j < hi; j += BLK) {
        unsigned e = (unsigned)ssd[j];
        int p = atomicAdd(&cur[e & 255], 1);  // LDS returning atomic
        col[p] = (int)(e >> 8);
    }
}

// --- all three weights -> bf16 transposed, one launch ---------------------
__global__ void wconv_all(const float* __restrict__ W1, const float* __restrict__ W2,
                          const float* __restrict__ W3, bf16* __restrict__ WT1,
                          bf16* __restrict__ WT2, bf16* __restrict__ WT3) {
    int idx = blockIdx.x * blockDim.x + threadIdx.x;
    if (idx < 4096) {
        int k = idx >> 6, c = idx & 63;
        WT1[c * 64 + k] = __float2bfloat16(W1[idx]);
    } else if (idx < 8192) {
        int i = idx - 4096, k = i >> 6, c = i & 63;
        WT2[c * 64 + k] = __float2bfloat16(W2[i]);
    } else if (idx < 10240) {
        int i = idx - 8192, k = i >> 5, c = i & 31;
        WT3[c * 64 + k] = __float2bfloat16(W3[i]);
    }
}

// --- MFMA GEMM (layer 1, f32 input): hlin = dinv * (x @ W1) --------------
template <int DOUT, bool AF32>
__global__ void mfma_gemm(const void* __restrict__ inv, const bf16* __restrict__ WT,
                          const float* __restrict__ dinv, bf16* __restrict__ hlin, int n) {
    constexpr int NT = DOUT / 16;
    const int lane = threadIdx.x & 63;
    const int wave = threadIdx.x >> 6;
    const int q = lane >> 4;
    const int l16 = lane & 15;
    const int row0 = blockIdx.x * 64 + wave * 16;

    int arow = row0 + l16;
    if (arow >= n) arow = n - 1;

    bf16x8 a0, a1;
    if (AF32) {
        const float* in = (const float*)inv;
        const float* p = in + (size_t)arow * 64 + q * 8;
        float4 f0 = *(const float4*)(p);
        float4 f1 = *(const float4*)(p + 4);
        float4 g0 = *(const float4*)(p + 32);
        float4 g1 = *(const float4*)(p + 36);
        bf16 t0[8] = {__float2bfloat16(f0.x), __float2bfloat16(f0.y), __float2bfloat16(f0.z), __float2bfloat16(f0.w),
                      __float2bfloat16(f1.x), __float2bfloat16(f1.y), __float2bfloat16(f1.z), __float2bfloat16(f1.w)};
        bf16 t1[8] = {__float2bfloat16(g0.x), __float2bfloat16(g0.y), __float2bfloat16(g0.z), __float2bfloat16(g0.w),
                      __float2bfloat16(g1.x), __float2bfloat16(g1.y), __float2bfloat16(g1.z), __float2bfloat16(g1.w)};
        __builtin_memcpy(&a0, t0, 16);
        __builtin_memcpy(&a1, t1, 16);
    } else {
        const bf16* in = (const bf16*)inv;
        a0 = *(const bf16x8*)(in + (size_t)arow * 64 + q * 8);
        a1 = *(const bf16x8*)(in + (size_t)arow * 64 + 32 + q * 8);
    }

    f32x4 acc[NT];
#pragma unroll
    for (int ct = 0; ct < NT; ++ct) {
        const bf16* wrow = WT + (size_t)(ct * 16 + l16) * 64 + q * 8;
        bf16x8 b0 = *(const bf16x8*)(wrow);
        bf16x8 b1 = *(const bf16x8*)(wrow + 32);
        f32x4 c = {0.f, 0.f, 0.f, 0.f};
        c = __builtin_amdgcn_mfma_f32_16x16x32_bf16(a0, b0, c, 0, 0, 0);
        c = __builtin_amdgcn_mfma_f32_16x16x32_bf16(a1, b1, c, 0, 0, 0);
        acc[ct] = c;
    }

    float dv[4];
#pragma unroll
    for (int r = 0; r < 4; ++r) {
        int rr = row0 + q * 4 + r;
        dv[r] = (rr < n) ? dinv[rr] : 0.0f;
    }
#pragma unroll
    for (int ct = 0; ct < NT; ++ct) {
#pragma unroll
        for (int r = 0; r < 4; ++r) {
            int rr = row0 + q * 4 + r;
            if (rr < n)
                hlin[(size_t)rr * DOUT + ct * 16 + l16] = __float2bfloat16(acc[ct][r] * dv[r]);
        }
    }
}

// --- FUSED: pull-agg (64 feats, 4 nodes/wave, 4-deep) + next-layer GEMM ---
// Block = 4 waves = 16 nodes = one MFMA M-tile. After the agg epilogue,
// g==0 lanes write bf16(vals) into a padded LDS tile [16][72] (identical
// rounding to the old actb), then each wave computes a 16x16 tile of
// vals @ WTn, scales by dinv[row], stores next hlin. Deletes actb traffic
// and the standalone GEMM launch. DOUTN=32: only waves 0,1 run the MFMA.
template <int DOUTN, bool LEAKY>
__global__ __launch_bounds__(256, 8)
void agg_gemm_kernel(const int* __restrict__ row_ptr, const int* __restrict__ deg,
                     const int* __restrict__ col, const bf16* __restrict__ hlin,
                     const float* __restrict__ dinv, const float* __restrict__ b,
                     float* __restrict__ out, const bf16* __restrict__ WTn,
                     bf16* __restrict__ hout, int n) {
    __shared__ short tile[16 * 72];      // 144B row stride: conflict-free A-reads
    const int wave = threadIdx.x >> 6;
    const int lane = threadIdx.x & 63;
    const int sub = lane >> 4;           // node slot 0..3
    const int g = (lane >> 3) & 1;       // edge group 0..1
    const int fl = lane & 7;             // feature block fl*8..+7
    const int base = blockIdx.x * 16;
    const int node = base + wave * 4 + sub;
    const int PAD = n;                   // zero row (64-feat layout)

    const bool valid = node < n;
    const int nc = valid ? node : n - 1;
    const int beg = row_ptr[nc];
    const int dg = valid ? deg[nc] : 0;
    const int end = beg + dg;

    float acc[8], acc2[8];
    {   // self loop: g==0 lanes read own row; g==1 lanes read zero PAD row
        int c0 = (valid && g == 0) ? node : PAD;
        bf16x8 sv = *(const bf16x8*)(hlin + (size_t)c0 * 64 + (fl << 3));
#pragma unroll
        for (int k = 0; k < 8; ++k) { acc[k] = s2f(sv[k]); acc2[k] = 0.0f; }
    }

    // shared iteration count: max deg over this wave's 4 nodes
    int m = dg;
    m = max(m, __shfl_xor(m, 16));
    m = max(m, __shfl_xor(m, 32));
    const int iters = (m + 7) >> 3;      // 4 edges/group/iter

    int idx = beg + g;
    int c0 = col[idx     < end ? idx     : 0];
    int c1 = col[idx + 2 < end ? idx + 2 : 0];
    int c2 = col[idx + 4 < end ? idx + 4 : 0];
    int c3 = col[idx + 6 < end ? idx + 6 : 0];
    for (int j = 0; j < iters; ++j) {
        const int a0i = (idx     < end) ? c0 : PAD;
        const int a1i = (idx + 2 < end) ? c1 : PAD;
        const int a2i = (idx + 4 < end) ? c2 : PAD;
        const int a3i = (idx + 6 < end) ? c3 : PAD;
        idx += 8;
        c0 = col[idx     < end ? idx     : 0];   // prefetch next quad
        c1 = col[idx + 2 < end ? idx + 2 : 0];
        c2 = col[idx + 4 < end ? idx + 4 : 0];
        c3 = col[idx + 6 < end ? idx + 6 : 0];
        bf16x8 v0 = *(const bf16x8*)(hlin + (size_t)a0i * 64 + (fl << 3));
        bf16x8 v1 = *(const bf16x8*)(hlin + (size_t)a1i * 64 + (fl << 3));
        bf16x8 v2 = *(const bf16x8*)(hlin + (size_t)a2i * 64 + (fl << 3));
        bf16x8 v3 = *(const bf16x8*)(hlin + (size_t)a3i * 64 + (fl << 3));
#pragma unroll
        for (int k = 0; k < 8; ++k) {
            acc[k]  += s2f(v0[k]) + s2f(v1[k]);
            acc2[k] += s2f(v2[k]) + s2f(v3[k]);
        }
    }

#pragma unroll
    for (int k = 0; k < 8; ++k) acc[k] += acc2[k];
#pragma unroll
    for (int k = 0; k < 8; ++k) acc[k] += __shfl_xor(acc[k], 8);

    const float dv = dinv[nc];
    const float4 bb0 = *(const float4*)(b + (fl << 3));
    const float4 bb1 = *(const float4*)(b + (fl << 3) + 4);
    float vals[8];
    vals[0] = acc[0] * dv + bb0.x;
    vals[1] = acc[1] * dv + bb0.y;
    vals[2] = acc[2] * dv + bb0.z;
    vals[3] = acc[3] * dv + bb0.w;
    vals[4] = acc[4] * dv + bb1.x;
    vals[5] = acc[5] * dv + bb1.y;
    vals[6] = acc[6] * dv + bb1.z;
    vals[7] = acc[7] * dv + bb1.w;
    if (LEAKY) {
#pragma unroll
        for (int k = 0; k < 8; ++k) vals[k] = (vals[k] >= 0.0f) ? vals[k] : 0.01f * vals[k];
    }
    if (g == 0) {
        bf16x8 ob;
#pragma unroll
        for (int k = 0; k < 8; ++k) ob[k] = f2s(vals[k]);
        // LDS tile write (always, so A-rows are initialized even off-tail)
        *(bf16x8*)(tile + (wave * 4 + sub) * 72 + (fl << 3)) = ob;
        if (valid) {                     // 4 nodes store in parallel: 1KB/wave
            float* op = out + (size_t)node * 64 + (fl << 3);
            f32x4 o0 = {vals[0], vals[1], vals[2], vals[3]};
            f32x4 o1 = {vals[4], vals[5], vals[6], vals[7]};
            __builtin_nontemporal_store(o0, (f32x4*)op);   // out never re-read
            __builtin_nontemporal_store(o1, (f32x4*)(op + 4));
        }
    }
    __syncthreads();

    // --- GEMM epilogue: hout[16 x DOUTN] = dinv * (tile @ WTn) ---
    const int q = sub;                   // lane>>4
    const int l16 = lane & 15;
    if (DOUTN == 64 || wave < 2) {
        bf16x8 a0 = *(const bf16x8*)(tile + l16 * 72 + q * 8);
        bf16x8 a1 = *(const bf16x8*)(tile + l16 * 72 + 32 + q * 8);
        const bf16* wrow = WTn + (size_t)(wave * 16 + l16) * 64 + q * 8;
        bf16x8 b0 = *(const bf16x8*)(wrow);
        bf16x8 b1 = *(const bf16x8*)(wrow + 32);
        f32x4 c = {0.f, 0.f, 0.f, 0.f};
        c = __builtin_amdgcn_mfma_f32_16x16x32_bf16(a0, b0, c, 0, 0, 0);
        c = __builtin_amdgcn_mfma_f32_16x16x32_bf16(a1, b1, c, 0, 0, 0);
#pragma unroll
        for (int r = 0; r < 4; ++r) {
            int rr = base + q * 4 + r;
            if (rr < n)
                hout[(size_t)rr * DOUTN + wave * 16 + l16] = __float2bfloat16(c[r] * dinv[rr]);
        }
    }
}

// --- Pull aggregation, 32 feats, 4 nodes per wave, 4-deep pipeline --------
__global__ __launch_bounds__(256, 8)
void agg32_kernel(const int* __restrict__ row_ptr, const int* __restrict__ deg,
                  const int* __restrict__ col, const bf16* __restrict__ hlin,
                  const float* __restrict__ dinv, const float* __restrict__ b,
                  float* __restrict__ out, int n) {
    const int wid = (blockIdx.x * blockDim.x + threadIdx.x) >> 6;
    const int lane = threadIdx.x & 63;
    const int sub = lane >> 4;
    const int g = (lane >> 3) & 1;
    const int fl = lane & 7;             // feature block fl*4..+3
    const int node = wid * 4 + sub;
    const int PAD = 2 * n;               // zero row (32-feat layout)

    const bool valid = node < n;
    const int nc = valid ? node : n - 1;
    const int beg = row_ptr[nc];
    const int dg = valid ? deg[nc] : 0;
    const int end = beg + dg;

    float acc[4], acc2[4];
    {
        int c0 = (valid && g == 0) ? node : PAD;
        bf16x4 sv = *(const bf16x4*)(hlin + (size_t)c0 * 32 + (fl << 2));
#pragma unroll
        for (int k = 0; k < 4; ++k) { acc[k] = s2f(sv[k]); acc2[k] = 0.0f; }
    }

    int m = dg;
    m = max(m, __shfl_xor(m, 16));
    m = max(m, __shfl_xor(m, 32));
    const int iters = (m + 7) >> 3;

    int idx = beg + g;
    int c0 = col[idx     < end ? idx     : 0];
    int c1 = col[idx + 2 < end ? idx + 2 : 0];
    int c2 = col[idx + 4 < end ? idx + 4 : 0];
    int c3 = col[idx + 6 < end ? idx + 6 : 0];
    for (int j = 0; j < iters; ++j) {
        const int a0 = (idx     < end) ? c0 : PAD;
        const int a1 = (idx + 2 < end) ? c1 : PAD;
        const int a2 = (idx + 4 < end) ? c2 : PAD;
        const int a3 = (idx + 6 < end) ? c3 : PAD;
        idx += 8;
        c0 = col[idx     < end ? idx     : 0];
        c1 = col[idx + 2 < end ? idx + 2 : 0];
        c2 = col[idx + 4 < end ? idx + 4 : 0];
        c3 = col[idx + 6 < end ? idx + 6 : 0];
        bf16x4 v0 = *(const bf16x4*)(hlin + (size_t)a0 * 32 + (fl << 2));
        bf16x4 v1 = *(const bf16x4*)(hlin + (size_t)a1 * 32 + (fl << 2));
        bf16x4 v2 = *(const bf16x4*)(hlin + (size_t)a2 * 32 + (fl << 2));
        bf16x4 v3 = *(const bf16x4*)(hlin + (size_t)a3 * 32 + (fl << 2));
#pragma unroll
        for (int k = 0; k < 4; ++k) {
            acc[k]  += s2f(v0[k]) + s2f(v1[k]);
            acc2[k] += s2f(v2[k]) + s2f(v3[k]);
        }
    }

#pragma unroll
    for (int k = 0; k < 4; ++k) acc[k] += acc2[k];
#pragma unroll
    for (int k = 0; k < 4; ++k) acc[k] += __shfl_xor(acc[k], 8);

    const float dv = dinv[nc];
    const float4 bb = *(const float4*)(b + (fl << 2));
    float vals[4];
    vals[0] = acc[0] * dv + bb.x;
    vals[1] = acc[1] * dv + bb.y;
    vals[2] = acc[2] * dv + bb.z;
    vals[3] = acc[3] * dv + bb.w;
    if (valid && g == 0) {               // 4 x 128B contiguous per wave
        f32x4 o = {vals[0], vals[1], vals[2], vals[3]};
        __builtin_nontemporal_store(o, (f32x4*)(out + (size_t)node * 32 + (fl << 2)));
    }
}

extern "C" void kernel_launch(void* const* d_in, const int* in_sizes, int n_in,
                              void* d_out, int out_size, void* d_ws, size_t ws_size,
                              hipStream_t stream) {
    const float* x  = (const float*)d_in[0];
    const int*   ei = (const int*)d_in[1];
    const float* W1 = (const float*)d_in[2];
    const float* b1 = (const float*)d_in[3];
    const float* W2 = (const float*)d_in[4];
    const float* b2 = (const float*)d_in[5];
    const float* W3 = (const float*)d_in[6];
    const float* b3 = (const float*)d_in[7];
    float* out = (float*)d_out;

    const int N = in_sizes[0] / 64;   // 100000
    const int E = in_sizes[1] / 2;    // 1600000
    const int* src = ei;
    const int* dst = ei + E;

    const int NB  = (N + 255) >> 8;           // buckets (<=512 for N<=131072)
    const int EPB = (E + NBLK - 1) / NBLK;    // edges per partition block

    char* w = (char*)d_ws;
    auto take = [&](size_t bytes) { char* p = w; w += (bytes + 15) & ~(size_t)15; return p; };
    int*   col       = (int*)take((size_t)E * 4);
    int*   ssd       = (int*)take((size_t)E * 4);   // packed (src<<8)|(dst&255)
    bf16*  hlinA     = (bf16*)take(((size_t)N * 64 + 64) * 2);  // +64 hw: PAD row
    bf16*  hlinB     = (bf16*)take(((size_t)N * 64 + 64) * 2);  // +64 hw: PAD row
    bf16*  WT1       = (bf16*)take(64 * 64 * 2);
    bf16*  WT2       = (bf16*)take(64 * 64 * 2);
    bf16*  WT3       = (bf16*)take(32 * 64 * 2);
    int*   deg       = (int*)take((size_t)N * 4);
    int*   row_ptr   = (int*)take((size_t)N * 4);
    float* dinv      = (float*)take((size_t)N * 4);
    int*   blockhist = (int*)take((size_t)NB * NBLK * 4);
    int*   btotal    = (int*)take((size_t)SCAN2_T * 4);

    float* out0 = out;
    float* out1 = out + (size_t)N * 64;
    float* out2 = out + (size_t)N * 128;

    const int gemmBlocks = (N + 63) / 64;
    const int fusedBlocks = (N + 15) / 16;    // 16 nodes per block (4 waves x 4)
    const int aggWaves = (N + 3) / 4;
    const int aggBlocks = (aggWaves * 64 + BLK - 1) / BLK;

    // zero PAD rows of both hlin buffers: halfwords [64N, 64N+64)
    hipMemsetAsync(hlinA + (size_t)N * 64, 0, 128, stream);
    hipMemsetAsync(hlinB + (size_t)N * 64, 0, 128, stream);

    // --- CSR build: bucketed counting sort, LDS atomics only ---
    bucket_hist<<<NBLK, BLK, 0, stream>>>(dst, blockhist, E, EPB, NB);
    colscan_kernel<<<NB, SCAN2_T, 0, stream>>>(blockhist, btotal);
    scan2_kernel<<<1, SCAN2_T, 0, stream>>>(btotal, NB);       // -> bucket bases
    bucket_scatter<<<NBLK, BLK, 0, stream>>>(src, dst, blockhist, btotal, ssd, E, EPB, NB);
    bucket_csr<<<NB, BLK, 0, stream>>>(ssd, btotal, col, deg, row_ptr, dinv, N, E, NB);

    // --- weights -> bf16 transposed ---
    wconv_all<<<40, BLK, 0, stream>>>(W1, W2, W3, WT1, WT2, WT3);

    // --- layer 1 GEMM: hlinA = dinv * (x @ W1) ---
    mfma_gemm<64, true><<<gemmBlocks, BLK, 0, stream>>>(x, WT1, dinv, hlinA, N);

    // --- fused: agg(hlinA)->out0 + GEMM(W2)->hlinB ---
    agg_gemm_kernel<64, true><<<fusedBlocks, BLK, 0, stream>>>(
        row_ptr, deg, col, hlinA, dinv, b1, out0, WT2, hlinB, N);

    // --- fused: agg(hlinB)->out1 + GEMM(W3)->hlinA (32-col) ---
    agg_gemm_kernel<32, true><<<fusedBlocks, BLK, 0, stream>>>(
        row_ptr, deg, col, hlinB, dinv, b2, out1, WT3, hlinA, N);

    // --- layer 3 agg: out2 = agg(hlinA 32-col) + b3 ---
    agg32_kernel<<<aggBlocks, BLK, 0, stream>>>(
        row_ptr, deg, col, hlinA, dinv, b3, out2, N);
}

// Round 9
// 253.722 us; speedup vs baseline: 1.7097x; 1.0281x over previous
//
#include <hip/hip_runtime.h>
#include <hip/hip_bf16.h>

typedef __hip_bfloat16 bf16;
typedef __attribute__((ext_vector_type(8))) short bf16x8;
typedef __attribute__((ext_vector_type(4))) short bf16x4;
typedef __attribute__((ext_vector_type(4))) float f32x4;

constexpr int BLK = 256;
constexpr int SCAN2_T = 512;
constexpr int NBLK = 400;      // edge-partition blocks for hist/scatter
// buckets: dst>>8, 256 nodes per bucket. Requires N <= 512*256 = 131072.
// packed ssd entry: (src<<8)|(dst&255) -- needs N <= 2^17 (src fits 17 bits).

__device__ inline float s2f(short s) {
    union { unsigned u; float f; } z;
    z.u = ((unsigned)(unsigned short)s) << 16;
    return z.f;
}
__device__ inline short f2s(float f) {
    union { bf16 h; short s; } u;
    u.h = __float2bfloat16(f);
    return u.s;
}

// 256-thread loader + exclusive scan of btotal[0..NB) into LDS s[512].
// Two half-scans + carry; all cross-thread reads fenced from writes.
__device__ inline void load_exscan512(int* s, const int* __restrict__ btotal,
                                      int NB, int t) {
    int v0 = (t < NB) ? btotal[t] : 0;
    int v1 = (t + 256 < NB) ? btotal[t + 256] : 0;
    s[t] = v0; s[t + 256] = v1;
    __syncthreads();
    for (int off = 1; off < 256; off <<= 1) {
        int a0 = (t >= off) ? s[t - off] : 0;
        int a1 = (t >= off) ? s[256 + t - off] : 0;
        __syncthreads();
        s[t] += a0; s[256 + t] += a1;
        __syncthreads();
    }
    int carry = s[255];
    int inc0 = s[t], inc1 = s[256 + t];
    __syncthreads();
    s[t] = inc0 - v0;
    s[256 + t] = inc1 + carry - v1;
    __syncthreads();
}

// --- Phase A: per-block LDS histogram of dst buckets; extra blocks do the
// weight bf16-transpose and zero the PAD rows (merged launches). ----------
__global__ void bucket_histw(const int* __restrict__ dst, int* __restrict__ blockhist,
                             const float* __restrict__ W1, const float* __restrict__ W2,
                             const float* __restrict__ W3, bf16* __restrict__ WT1,
                             bf16* __restrict__ WT2, bf16* __restrict__ WT3,
                             bf16* __restrict__ padA, bf16* __restrict__ padB,
                             int E, int EPB, int NB) {
    if (blockIdx.x >= NBLK) {   // weight conversion + PAD zeroing blocks
        int idx = (blockIdx.x - NBLK) * BLK + threadIdx.x;
        if (idx < 4096) {
            int k = idx >> 6, c = idx & 63;
            WT1[c * 64 + k] = __float2bfloat16(W1[idx]);
        } else if (idx < 8192) {
            int i = idx - 4096, k = i >> 6, c = i & 63;
            WT2[c * 64 + k] = __float2bfloat16(W2[i]);
        } else if (idx < 10240) {
            int i = idx - 8192, k = i >> 5, c = i & 31;
            WT3[c * 64 + k] = __float2bfloat16(W3[i]);
        } else if (idx < 10304) {
            padA[idx - 10240] = __float2bfloat16(0.0f);
        } else if (idx < 10368) {
            padB[idx - 10304] = __float2bfloat16(0.0f);
        }
        return;
    }
    __shared__ int h[512];
    for (int i = threadIdx.x; i < NB; i += BLK) h[i] = 0;
    __syncthreads();
    int lo = blockIdx.x * EPB;
    int hi = min(E, lo + EPB);
    for (int t = lo + threadIdx.x; t < hi; t += BLK)
        atomicAdd(&h[dst[t] >> 8], 1);
    __syncthreads();
    for (int i = threadIdx.x; i < NB; i += BLK)
        blockhist[i * NBLK + blockIdx.x] = h[i];   // [bucket][blk]
}

// --- Phase A2: per-bucket exclusive scan over blocks; bucket total out. ---
__global__ void colscan_kernel(int* __restrict__ blockhist, int* __restrict__ btotal) {
    __shared__ int s[SCAN2_T];
    int b = blockIdx.x;
    int t = threadIdx.x;
    int v = (t < NBLK) ? blockhist[b * NBLK + t] : 0;
    s[t] = v;
    __syncthreads();
    for (int off = 1; off < SCAN2_T; off <<= 1) {
        int add = (t >= off) ? s[t - off] : 0;
        __syncthreads();
        s[t] += add;
        __syncthreads();
    }
    if (t < NBLK) blockhist[b * NBLK + t] = s[t] - v;   // exclusive
    if (t == SCAN2_T - 1) btotal[b] = s[SCAN2_T - 1];   // bucket total
}

// --- Phase B: scatter edges into bucket-sorted order (LDS cursors). ------
// Bucket bases derived in-block from btotal via LDS scan (scan2 deleted).
__global__ void bucket_scatter(const int* __restrict__ src, const int* __restrict__ dst,
                               const int* __restrict__ blockhist, const int* __restrict__ btotal,
                               int* __restrict__ ssd, int E, int EPB, int NB) {
    __shared__ int s[512];
    __shared__ int h[512];
    load_exscan512(s, btotal, NB, threadIdx.x);
    for (int i = threadIdx.x; i < NB; i += BLK)
        h[i] = s[i] + blockhist[i * NBLK + blockIdx.x];
    __syncthreads();
    int lo = blockIdx.x * EPB;
    int hi = min(E, lo + EPB);
    for (int t = lo + threadIdx.x; t < hi; t += BLK) {
        int d = dst[t];
        int pos = atomicAdd(&h[d >> 8], 1);    // LDS returning atomic
        ssd[pos] = (src[t] << 8) | (d & 255);
    }
}

// --- Phase C: per-bucket CSR build + FUSED layer-1 GEMM ------------------
// Block b owns nodes [b*256, b*256+256) = 16 MFMA M-tiles. After emitting
// col/deg/row_ptr/dinv, its 4 waves compute hlinA = dinv * (x @ W1) for
// those rows (identical numeric path to the old standalone mfma_gemm).
__global__ void bucket_csr_gemm(const int* __restrict__ ssd, const int* __restrict__ btotal,
                                int* __restrict__ col, int* __restrict__ deg,
                                int* __restrict__ row_ptr, float* __restrict__ dinv,
                                const float* __restrict__ x, const bf16* __restrict__ WT1,
                                bf16* __restrict__ hlinA, int N, int E, int NB) {
    __shared__ int s[512];
    __shared__ int dloc[256];
    __shared__ int ss[256];
    __shared__ int cur[256];
    __shared__ float dvs[256];
    int b = blockIdx.x;
    int t = threadIdx.x;
    load_exscan512(s, btotal, NB, t);
    int lo = s[b];
    int hi = (b + 1 < NB) ? s[b + 1] : E;
    dloc[t] = 0;
    __syncthreads();
    for (int j = lo + t; j < hi; j += BLK)
        atomicAdd(&dloc[ssd[j] & 255], 1);
    __syncthreads();
    int own = dloc[t];
    ss[t] = own;
    __syncthreads();
    for (int off = 1; off < 256; off <<= 1) {
        int add = (t >= off) ? ss[t - off] : 0;
        __syncthreads();
        ss[t] += add;
        __syncthreads();
    }
    int excl = ss[t] - own;
    cur[t] = lo + excl;
    int node = (b << 8) + t;
    float dvloc = rsqrtf((float)own + 1.0f);
    dvs[t] = dvloc;
    if (node < N) {
        deg[node] = own;
        row_ptr[node] = lo + excl;
        dinv[node] = dvloc;
    }
    __syncthreads();
    for (int j = lo + t; j < hi; j += BLK) {
        unsigned e = (unsigned)ssd[j];
        int p = atomicAdd(&cur[e & 255], 1);  // LDS returning atomic
        col[p] = (int)(e >> 8);
    }
    __syncthreads();

    // --- fused layer-1 GEMM for this block's 256 nodes ---
    const int wave = t >> 6;
    const int lane = t & 63;
    const int q = lane >> 4;
    const int l16 = lane & 15;
#pragma unroll
    for (int mt0 = 0; mt0 < 4; ++mt0) {
        const int mt = wave * 4 + mt0;         // M-tile 0..15
        const int rowbase = (b << 8) + mt * 16;
        int arow = rowbase + l16;
        if (arow >= N) arow = N - 1;
        const float* p = x + (size_t)arow * 64 + q * 8;
        float4 f0 = *(const float4*)(p);
        float4 f1 = *(const float4*)(p + 4);
        float4 g0 = *(const float4*)(p + 32);
        float4 g1 = *(const float4*)(p + 36);
        bf16 t0[8] = {__float2bfloat16(f0.x), __float2bfloat16(f0.y), __float2bfloat16(f0.z), __float2bfloat16(f0.w),
                      __float2bfloat16(f1.x), __float2bfloat16(f1.y), __float2bfloat16(f1.z), __float2bfloat16(f1.w)};
        bf16 t1[8] = {__float2bfloat16(g0.x), __float2bfloat16(g0.y), __float2bfloat16(g0.z), __float2bfloat16(g0.w),
                      __float2bfloat16(g1.x), __float2bfloat16(g1.y), __float2bfloat16(g1.z), __float2bfloat16(g1.w)};
        bf16x8 a0, a1;
        __builtin_memcpy(&a0, t0, 16);
        __builtin_memcpy(&a1, t1, 16);
#pragma unroll
        for (int ct = 0; ct < 4; ++ct) {
            const bf16* wrow = WT1 + (size_t)(ct * 16 + l16) * 64 + q * 8;
            bf16x8 b0 = *(const bf16x8*)(wrow);
            bf16x8 b1 = *(const bf16x8*)(wrow + 32);
            f32x4 c = {0.f, 0.f, 0.f, 0.f};
            c = __builtin_amdgcn_mfma_f32_16x16x32_bf16(a0, b0, c, 0, 0, 0);
            c = __builtin_amdgcn_mfma_f32_16x16x32_bf16(a1, b1, c, 0, 0, 0);
#pragma unroll
            for (int r = 0; r < 4; ++r) {
                int rr = rowbase + q * 4 + r;
                if (rr < N)
                    hlinA[(size_t)rr * 64 + ct * 16 + l16] =
                        __float2bfloat16(c[r] * dvs[mt * 16 + q * 4 + r]);
            }
        }
    }
}

// --- FUSED: pull-agg (64 feats, 4 nodes/wave, 4-deep) + next-layer GEMM ---
template <int DOUTN, bool LEAKY>
__global__ __launch_bounds__(256, 8)
void agg_gemm_kernel(const int* __restrict__ row_ptr, const int* __restrict__ deg,
                     const int* __restrict__ col, const bf16* __restrict__ hlin,
                     const float* __restrict__ dinv, const float* __restrict__ b,
                     float* __restrict__ out, const bf16* __restrict__ WTn,
                     bf16* __restrict__ hout, int n) {
    __shared__ short tile[16 * 72];      // 144B row stride: conflict-free A-reads
    const int wave = threadIdx.x >> 6;
    const int lane = threadIdx.x & 63;
    const int sub = lane >> 4;           // node slot 0..3
    const int g = (lane >> 3) & 1;       // edge group 0..1
    const int fl = lane & 7;             // feature block fl*8..+7
    const int base = blockIdx.x * 16;
    const int node = base + wave * 4 + sub;
    const int PAD = n;                   // zero row (64-feat layout)

    const bool valid = node < n;
    const int nc = valid ? node : n - 1;
    const int beg = row_ptr[nc];
    const int dg = valid ? deg[nc] : 0;
    const int end = beg + dg;

    float acc[8], acc2[8];
    {   // self loop: g==0 lanes read own row; g==1 lanes read zero PAD row
        int c0 = (valid && g == 0) ? node : PAD;
        bf16x8 sv = *(const bf16x8*)(hlin + (size_t)c0 * 64 + (fl << 3));
#pragma unroll
        for (int k = 0; k < 8; ++k) { acc[k] = s2f(sv[k]); acc2[k] = 0.0f; }
    }

    int m = dg;
    m = max(m, __shfl_xor(m, 16));
    m = max(m, __shfl_xor(m, 32));
    const int iters = (m + 7) >> 3;      // 4 edges/group/iter

    int idx = beg + g;
    int c0 = col[idx     < end ? idx     : 0];
    int c1 = col[idx + 2 < end ? idx + 2 : 0];
    int c2 = col[idx + 4 < end ? idx + 4 : 0];
    int c3 = col[idx + 6 < end ? idx + 6 : 0];
    for (int j = 0; j < iters; ++j) {
        const int a0i = (idx     < end) ? c0 : PAD;
        const int a1i = (idx + 2 < end) ? c1 : PAD;
        const int a2i = (idx + 4 < end) ? c2 : PAD;
        const int a3i = (idx + 6 < end) ? c3 : PAD;
        idx += 8;
        c0 = col[idx     < end ? idx     : 0];   // prefetch next quad
        c1 = col[idx + 2 < end ? idx + 2 : 0];
        c2 = col[idx + 4 < end ? idx + 4 : 0];
        c3 = col[idx + 6 < end ? idx + 6 : 0];
        bf16x8 v0 = *(const bf16x8*)(hlin + (size_t)a0i * 64 + (fl << 3));
        bf16x8 v1 = *(const bf16x8*)(hlin + (size_t)a1i * 64 + (fl << 3));
        bf16x8 v2 = *(const bf16x8*)(hlin + (size_t)a2i * 64 + (fl << 3));
        bf16x8 v3 = *(const bf16x8*)(hlin + (size_t)a3i * 64 + (fl << 3));
#pragma unroll
        for (int k = 0; k < 8; ++k) {
            acc[k]  += s2f(v0[k]) + s2f(v1[k]);
            acc2[k] += s2f(v2[k]) + s2f(v3[k]);
        }
    }

#pragma unroll
    for (int k = 0; k < 8; ++k) acc[k] += acc2[k];
#pragma unroll
    for (int k = 0; k < 8; ++k) acc[k] += __shfl_xor(acc[k], 8);

    const float dv = dinv[nc];
    const float4 bb0 = *(const float4*)(b + (fl << 3));
    const float4 bb1 = *(const float4*)(b + (fl << 3) + 4);
    float vals[8];
    vals[0] = acc[0] * dv + bb0.x;
    vals[1] = acc[1] * dv + bb0.y;
    vals[2] = acc[2] * dv + bb0.z;
    vals[3] = acc[3] * dv + bb0.w;
    vals[4] = acc[4] * dv + bb1.x;
    vals[5] = acc[5] * dv + bb1.y;
    vals[6] = acc[6] * dv + bb1.z;
    vals[7] = acc[7] * dv + bb1.w;
    if (LEAKY) {
#pragma unroll
        for (int k = 0; k < 8; ++k) vals[k] = (vals[k] >= 0.0f) ? vals[k] : 0.01f * vals[k];
    }
    if (g == 0) {
        bf16x8 ob;
#pragma unroll
        for (int k = 0; k < 8; ++k) ob[k] = f2s(vals[k]);
        *(bf16x8*)(tile + (wave * 4 + sub) * 72 + (fl << 3)) = ob;
        if (valid) {                     // 4 nodes store in parallel: 1KB/wave
            float* op = out + (size_t)node * 64 + (fl << 3);
            f32x4 o0 = {vals[0], vals[1], vals[2], vals[3]};
            f32x4 o1 = {vals[4], vals[5], vals[6], vals[7]};
            __builtin_nontemporal_store(o0, (f32x4*)op);   // out never re-read
            __builtin_nontemporal_store(o1, (f32x4*)(op + 4));
        }
    }
    __syncthreads();

    // --- GEMM epilogue: hout[16 x DOUTN] = dinv * (tile @ WTn) ---
    const int q = sub;                   // lane>>4
    const int l16 = lane & 15;
    if (DOUTN == 64 || wave < 2) {
        bf16x8 a0 = *(const bf16x8*)(tile + l16 * 72 + q * 8);
        bf16x8 a1 = *(const bf16x8*)(tile + l16 * 72 + 32 + q * 8);
        const bf16* wrow = WTn + (size_t)(wave * 16 + l16) * 64 + q * 8;
        bf16x8 b0 = *(const bf16x8*)(wrow);
        bf16x8 b1 = *(const bf16x8*)(wrow + 32);
        f32x4 c = {0.f, 0.f, 0.f, 0.f};
        c = __builtin_amdgcn_mfma_f32_16x16x32_bf16(a0, b0, c, 0, 0, 0);
        c = __builtin_amdgcn_mfma_f32_16x16x32_bf16(a1, b1, c, 0, 0, 0);
#pragma unroll
        for (int r = 0; r < 4; ++r) {
            int rr = base + q * 4 + r;
            if (rr < n)
                hout[(size_t)rr * DOUTN + wave * 16 + l16] = __float2bfloat16(c[r] * dinv[rr]);
        }
    }
}

// --- Pull aggregation, 32 feats, 4 nodes per wave, 4-deep pipeline --------
__global__ __launch_bounds__(256, 8)
void agg32_kernel(const int* __restrict__ row_ptr, const int* __restrict__ deg,
                  const int* __restrict__ col, const bf16* __restrict__ hlin,
                  const float* __restrict__ dinv, const float* __restrict__ b,
                  float* __restrict__ out, int n) {
    const int wid = (blockIdx.x * blockDim.x + threadIdx.x) >> 6;
    const int lane = threadIdx.x & 63;
    const int sub = lane >> 4;
    const int g = (lane >> 3) & 1;
    const int fl = lane & 7;             // feature block fl*4..+3
    const int node = wid * 4 + sub;
    const int PAD = 2 * n;               // zero row (32-feat layout)

    const bool valid = node < n;
    const int nc = valid ? node : n - 1;
    const int beg = row_ptr[nc];
    const int dg = valid ? deg[nc] : 0;
    const int end = beg + dg;

    float acc[4], acc2[4];
    {
        int c0 = (valid && g == 0) ? node : PAD;
        bf16x4 sv = *(const bf16x4*)(hlin + (size_t)c0 * 32 + (fl << 2));
#pragma unroll
        for (int k = 0; k < 4; ++k) { acc[k] = s2f(sv[k]); acc2[k] = 0.0f; }
    }

    int m = dg;
    m = max(m, __shfl_xor(m, 16));
    m = max(m, __shfl_xor(m, 32));
    const int iters = (m + 7) >> 3;

    int idx = beg + g;
    int c0 = col[idx     < end ? idx     : 0];
    int c1 = col[idx + 2 < end ? idx + 2 : 0];
    int c2 = col[idx + 4 < end ? idx + 4 : 0];
    int c3 = col[idx + 6 < end ? idx + 6 : 0];
    for (int j = 0; j < iters; ++j) {
        const int a0 = (idx     < end) ? c0 : PAD;
        const int a1 = (idx + 2 < end) ? c1 : PAD;
        const int a2 = (idx + 4 < end) ? c2 : PAD;
        const int a3 = (idx + 6 < end) ? c3 : PAD;
        idx += 8;
        c0 = col[idx     < end ? idx     : 0];
        c1 = col[idx + 2 < end ? idx + 2 : 0];
        c2 = col[idx + 4 < end ? idx + 4 : 0];
        c3 = col[idx + 6 < end ? idx + 6 : 0];
        bf16x4 v0 = *(const bf16x4*)(hlin + (size_t)a0 * 32 + (fl << 2));
        bf16x4 v1 = *(const bf16x4*)(hlin + (size_t)a1 * 32 + (fl << 2));
        bf16x4 v2 = *(const bf16x4*)(hlin + (size_t)a2 * 32 + (fl << 2));
        bf16x4 v3 = *(const bf16x4*)(hlin + (size_t)a3 * 32 + (fl << 2));
#pragma unroll
        for (int k = 0; k < 4; ++k) {
            acc[k]  += s2f(v0[k]) + s2f(v1[k]);
            acc2[k] += s2f(v2[k]) + s2f(v3[k]);
        }
    }

#pragma unroll
    for (int k = 0; k < 4; ++k) acc[k] += acc2[k];
#pragma unroll
    for (int k = 0; k < 4; ++k) acc[k] += __shfl_xor(acc[k], 8);

    const float dv = dinv[nc];
    const float4 bb = *(const float4*)(b + (fl << 2));
    float vals[4];
    vals[0] = acc[0] * dv + bb.x;
    vals[1] = acc[1] * dv + bb.y;
    vals[2] = acc[2] * dv + bb.z;
    vals[3] = acc[3] * dv + bb.w;
    if (valid && g == 0) {               // 4 x 128B contiguous per wave
        f32x4 o = {vals[0], vals[1], vals[2], vals[3]};
        __builtin_nontemporal_store(o, (f32x4*)(out + (size_t)node * 32 + (fl << 2)));
    }
}

extern "C" void kernel_launch(void* const* d_in, const int* in_sizes, int n_in,
                              void* d_out, int out_size, void* d_ws, size_t ws_size,
                              hipStream_t stream) {
    const float* x  = (const float*)d_in[0];
    const int*   ei = (const int*)d_in[1];
    const float* W1 = (const float*)d_in[2];
    const float* b1 = (const float*)d_in[3];
    const float* W2 = (const float*)d_in[4];
    const float* b2 = (const float*)d_in[5];
    const float* W3 = (const float*)d_in[6];
    const float* b3 = (const float*)d_in[7];
    float* out = (float*)d_out;

    const int N = in_sizes[0] / 64;   // 100000
    const int E = in_sizes[1] / 2;    // 1600000
    const int* src = ei;
    const int* dst = ei + E;

    const int NB  = (N + 255) >> 8;           // buckets (<=512 for N<=131072)
    const int EPB = (E + NBLK - 1) / NBLK;    // edges per partition block

    char* w = (char*)d_ws;
    auto take = [&](size_t bytes) { char* p = w; w += (bytes + 15) & ~(size_t)15; return p; };
    int*   col       = (int*)take((size_t)E * 4);
    int*   ssd       = (int*)take((size_t)E * 4);   // packed (src<<8)|(dst&255)
    bf16*  hlinA     = (bf16*)take(((size_t)N * 64 + 64) * 2);  // +64 hw: PAD row
    bf16*  hlinB     = (bf16*)take(((size_t)N * 64 + 64) * 2);  // +64 hw: PAD row
    bf16*  WT1       = (bf16*)take(64 * 64 * 2);
    bf16*  WT2       = (bf16*)take(64 * 64 * 2);
    bf16*  WT3       = (bf16*)take(32 * 64 * 2);
    int*   deg       = (int*)take((size_t)N * 4);
    int*   row_ptr   = (int*)take((size_t)N * 4);
    float* dinv      = (float*)take((size_t)N * 4);
    int*   blockhist = (int*)take((size_t)NB * NBLK * 4);
    int*   btotal    = (int*)take((size_t)SCAN2_T * 4);

    float* out0 = out;
    float* out1 = out + (size_t)N * 64;
    float* out2 = out + (size_t)N * 128;

    const int fusedBlocks = (N + 15) / 16;    // 16 nodes per block (4 waves x 4)
    const int aggWaves = (N + 3) / 4;
    const int aggBlocks = (aggWaves * 64 + BLK - 1) / BLK;

    // --- build + weights + PAD (merged): 7 total dispatches ---
    bucket_histw<<<NBLK + 41, BLK, 0, stream>>>(
        dst, blockhist, W1, W2, W3, WT1, WT2, WT3,
        hlinA + (size_t)N * 64, hlinB + (size_t)N * 64, E, EPB, NB);
    colscan_kernel<<<NB, SCAN2_T, 0, stream>>>(blockhist, btotal);
    bucket_scatter<<<NBLK, BLK, 0, stream>>>(src, dst, blockhist, btotal, ssd, E, EPB, NB);
    bucket_csr_gemm<<<NB, BLK, 0, stream>>>(ssd, btotal, col, deg, row_ptr, dinv,
                                            x, WT1, hlinA, N, E, NB);

    // --- fused: agg(hlinA)->out0 + GEMM(W2)->hlinB ---
    agg_gemm_kernel<64, true><<<fusedBlocks, BLK, 0, stream>>>(
        row_ptr, deg, col, hlinA, dinv, b1, out0, WT2, hlinB, N);

    // --- fused: agg(hlinB)->out1 + GEMM(W3)->hlinA (32-col) ---
    agg_gemm_kernel<32, true><<<fusedBlocks, BLK, 0, stream>>>(
        row_ptr, deg, col, hlinB, dinv, b2, out1, WT3, hlinA, N);

    // --- layer 3 agg: out2 = agg(hlinA 32-col) + b3 ---
    agg32_kernel<<<aggBlocks, BLK, 0, stream>>>(
        row_ptr, deg, col, hlinA, dinv, b3, out2, N);
}

// Round 11
// 253.468 us; speedup vs baseline: 1.7114x; 1.0010x over previous
//
#include <hip/hip_runtime.h>
#include <hip/hip_bf16.h>

typedef __hip_bfloat16 bf16;
typedef __attribute__((ext_vector_type(8))) short bf16x8;
typedef __attribute__((ext_vector_type(4))) short bf16x4;
typedef __attribute__((ext_vector_type(4))) float f32x4;

constexpr int BLK = 256;
constexpr int SCAN2_T = 512;
constexpr int NBLK = 400;      // edge-partition blocks for hist/scatter
// buckets: dst>>8, 256 nodes per bucket. Requires N <= 512*256 = 131072.
// packed ssd entry: (src<<8)|(dst&255) -- needs N <= 2^17 (src fits 17 bits).

__device__ inline float s2f(short s) {
    union { unsigned u; float f; } z;
    z.u = ((unsigned)(unsigned short)s) << 16;
    return z.f;
}
__device__ inline short f2s(float f) {
    union { bf16 h; short s; } u;
    u.h = __float2bfloat16(f);
    return u.s;
}

// 256-thread loader + exclusive scan of btotal[0..NB) into LDS s[512].
__device__ inline void load_exscan512(int* s, const int* __restrict__ btotal,
                                      int NB, int t) {
    int v0 = (t < NB) ? btotal[t] : 0;
    int v1 = (t + 256 < NB) ? btotal[t + 256] : 0;
    s[t] = v0; s[t + 256] = v1;
    __syncthreads();
    for (int off = 1; off < 256; off <<= 1) {
        int a0 = (t >= off) ? s[t - off] : 0;
        int a1 = (t >= off) ? s[256 + t - off] : 0;
        __syncthreads();
        s[t] += a0; s[256 + t] += a1;
        __syncthreads();
    }
    int carry = s[255];
    int inc0 = s[t], inc1 = s[256 + t];
    __syncthreads();
    s[t] = inc0 - v0;
    s[256 + t] = inc1 + carry - v1;
    __syncthreads();
}

// --- Phase A: per-block LDS histogram of dst buckets; extra blocks do the
// weight bf16-transpose and zero the PAD rows (merged launches). ----------
__global__ void bucket_histw(const int* __restrict__ dst, int* __restrict__ blockhist,
                             const float* __restrict__ W1, const float* __restrict__ W2,
                             const float* __restrict__ W3, bf16* __restrict__ WT1,
                             bf16* __restrict__ WT2, bf16* __restrict__ WT3,
                             bf16* __restrict__ padA, bf16* __restrict__ padB,
                             int E, int EPB, int NB) {
    if (blockIdx.x >= NBLK) {   // weight conversion + PAD zeroing blocks
        int idx = (blockIdx.x - NBLK) * BLK + threadIdx.x;
        if (idx < 4096) {
            int k = idx >> 6, c = idx & 63;
            WT1[c * 64 + k] = __float2bfloat16(W1[idx]);
        } else if (idx < 8192) {
            int i = idx - 4096, k = i >> 6, c = i & 63;
            WT2[c * 64 + k] = __float2bfloat16(W2[i]);
        } else if (idx < 10240) {
            int i = idx - 8192, k = i >> 5, c = i & 31;
            WT3[c * 64 + k] = __float2bfloat16(W3[i]);
        } else if (idx < 10304) {
            padA[idx - 10240] = __float2bfloat16(0.0f);
        } else if (idx < 10368) {
            padB[idx - 10304] = __float2bfloat16(0.0f);
        }
        return;
    }
    __shared__ int h[512];
    for (int i = threadIdx.x; i < NB; i += BLK) h[i] = 0;
    __syncthreads();
    int lo = blockIdx.x * EPB;
    int hi = min(E, lo + EPB);
    for (int t = lo + threadIdx.x; t < hi; t += BLK)
        atomicAdd(&h[dst[t] >> 8], 1);
    __syncthreads();
    for (int i = threadIdx.x; i < NB; i += BLK)
        blockhist[i * NBLK + blockIdx.x] = h[i];   // [bucket][blk]
}

// --- Phase A2: per-bucket exclusive scan over blocks; bucket total out. ---
__global__ void colscan_kernel(int* __restrict__ blockhist, int* __restrict__ btotal) {
    __shared__ int s[SCAN2_T];
    int b = blockIdx.x;
    int t = threadIdx.x;
    int v = (t < NBLK) ? blockhist[b * NBLK + t] : 0;
    s[t] = v;
    __syncthreads();
    for (int off = 1; off < SCAN2_T; off <<= 1) {
        int add = (t >= off) ? s[t - off] : 0;
        __syncthreads();
        s[t] += add;
        __syncthreads();
    }
    if (t < NBLK) blockhist[b * NBLK + t] = s[t] - v;   // exclusive
    if (t == SCAN2_T - 1) btotal[b] = s[SCAN2_T - 1];   // bucket total
}

// --- Phase B: scatter edges into bucket-sorted order (LDS cursors). ------
__global__ void bucket_scatter(const int* __restrict__ src, const int* __restrict__ dst,
                               const int* __restrict__ blockhist, const int* __restrict__ btotal,
                               int* __restrict__ ssd, int E, int EPB, int NB) {
    __shared__ int s[512];
    __shared__ int h[512];
    load_exscan512(s, btotal, NB, threadIdx.x);
    for (int i = threadIdx.x; i < NB; i += BLK)
        h[i] = s[i] + blockhist[i * NBLK + blockIdx.x];
    __syncthreads();
    int lo = blockIdx.x * EPB;
    int hi = min(E, lo + EPB);
    for (int t = lo + threadIdx.x; t < hi; t += BLK) {
        int d = dst[t];
        int pos = atomicAdd(&h[d >> 8], 1);    // LDS returning atomic
        ssd[pos] = (src[t] << 8) | (d & 255);
    }
}

// --- Phase C: per-bucket CSR build + FUSED layer-1 GEMM ------------------
__global__ void bucket_csr_gemm(const int* __restrict__ ssd, const int* __restrict__ btotal,
                                int* __restrict__ col, int* __restrict__ deg,
                                int* __restrict__ row_ptr, float* __restrict__ dinv,
                                const float* __restrict__ x, const bf16* __restrict__ WT1,
                                bf16* __restrict__ hlinA, int N, int E, int NB) {
    __shared__ int s[512];
    __shared__ int dloc[256];
    __shared__ int ss[256];
    __shared__ int cur[256];
    __shared__ float dvs[256];
    int b = blockIdx.x;
    int t = threadIdx.x;
    load_exscan512(s, btotal, NB, t);
    int lo = s[b];
    int hi = (b + 1 < NB) ? s[b + 1] : E;
    dloc[t] = 0;
    __syncthreads();
    for (int j = lo + t; j < hi; j += BLK)
        atomicAdd(&dloc[ssd[j] & 255], 1);
    __syncthreads();
    int own = dloc[t];
    ss[t] = own;
    __syncthreads();
    for (int off = 1; off < 256; off <<= 1) {
        int add = (t >= off) ? ss[t - off] : 0;
        __syncthreads();
        ss[t] += add;
        __syncthreads();
    }
    int excl = ss[t] - own;
    cur[t] = lo + excl;
    int node = (b << 8) + t;
    float dvloc = rsqrtf((float)own + 1.0f);
    dvs[t] = dvloc;
    if (node < N) {
        deg[node] = own;
        row_ptr[node] = lo + excl;
        dinv[node] = dvloc;
    }
    __syncthreads();
    for (int j = lo + t; j < hi; j += BLK) {
        unsigned e = (unsigned)ssd[j];
        int p = atomicAdd(&cur[e & 255], 1);  // LDS returning atomic
        col[p] = (int)(e >> 8);
    }
    __syncthreads();

    // --- fused layer-1 GEMM for this block's 256 nodes ---
    const int wave = t >> 6;
    const int lane = t & 63;
    const int q = lane >> 4;
    const int l16 = lane & 15;
#pragma unroll
    for (int mt0 = 0; mt0 < 4; ++mt0) {
        const int mt = wave * 4 + mt0;         // M-tile 0..15
        const int rowbase = (b << 8) + mt * 16;
        int arow = rowbase + l16;
        if (arow >= N) arow = N - 1;
        const float* p = x + (size_t)arow * 64 + q * 8;
        float4 f0 = *(const float4*)(p);
        float4 f1 = *(const float4*)(p + 4);
        float4 g0 = *(const float4*)(p + 32);
        float4 g1 = *(const float4*)(p + 36);
        bf16 t0[8] = {__float2bfloat16(f0.x), __float2bfloat16(f0.y), __float2bfloat16(f0.z), __float2bfloat16(f0.w),
                      __float2bfloat16(f1.x), __float2bfloat16(f1.y), __float2bfloat16(f1.z), __float2bfloat16(f1.w)};
        bf16 t1[8] = {__float2bfloat16(g0.x), __float2bfloat16(g0.y), __float2bfloat16(g0.z), __float2bfloat16(g0.w),
                      __float2bfloat16(g1.x), __float2bfloat16(g1.y), __float2bfloat16(g1.z), __float2bfloat16(g1.w)};
        bf16x8 a0, a1;
        __builtin_memcpy(&a0, t0, 16);
        __builtin_memcpy(&a1, t1, 16);
#pragma unroll
        for (int ct = 0; ct < 4; ++ct) {
            const bf16* wrow = WT1 + (size_t)(ct * 16 + l16) * 64 + q * 8;
            bf16x8 b0 = *(const bf16x8*)(wrow);
            bf16x8 b1 = *(const bf16x8*)(wrow + 32);
            f32x4 c = {0.f, 0.f, 0.f, 0.f};
            c = __builtin_amdgcn_mfma_f32_16x16x32_bf16(a0, b0, c, 0, 0, 0);
            c = __builtin_amdgcn_mfma_f32_16x16x32_bf16(a1, b1, c, 0, 0, 0);
#pragma unroll
            for (int r = 0; r < 4; ++r) {
                int rr = rowbase + q * 4 + r;
                if (rr < N)
                    hlinA[(size_t)rr * 64 + ct * 16 + l16] =
                        __float2bfloat16(c[r] * dvs[mt * 16 + q * 4 + r]);
            }
        }
    }
}

// --- FUSED: pull-agg (64 feats, 4 nodes/wave, 4-deep) + next-layer GEMM ---
template <int DOUTN, bool LEAKY>
__global__ __launch_bounds__(256, 8)
void agg_gemm_kernel(const int* __restrict__ row_ptr, const int* __restrict__ deg,
                     const int* __restrict__ col, const bf16* __restrict__ hlin,
                     const float* __restrict__ dinv, const float* __restrict__ b,
                     float* __restrict__ out, const bf16* __restrict__ WTn,
                     bf16* __restrict__ hout, int n) {
    __shared__ short tile[16 * 72];      // 144B row stride: conflict-free A-reads
    const int wave = threadIdx.x >> 6;
    const int lane = threadIdx.x & 63;
    const int sub = lane >> 4;           // node slot 0..3
    const int g = (lane >> 3) & 1;       // edge group 0..1
    const int fl = lane & 7;             // feature block fl*8..+7
    const int base = blockIdx.x * 16;
    const int node = base + wave * 4 + sub;
    const int PAD = n;                   // zero row (64-feat layout)

    const bool valid = node < n;
    const int nc = valid ? node : n - 1;
    const int beg = row_ptr[nc];
    const int dg = valid ? deg[nc] : 0;
    const int end = beg + dg;

    float acc[8], acc2[8];
    {   // self loop: g==0 lanes read own row; g==1 lanes read zero PAD row
        int c0 = (valid && g == 0) ? node : PAD;
        bf16x8 sv = *(const bf16x8*)(hlin + (size_t)c0 * 64 + (fl << 3));
#pragma unroll
        for (int k = 0; k < 8; ++k) { acc[k] = s2f(sv[k]); acc2[k] = 0.0f; }
    }

    int m = dg;
    m = max(m, __shfl_xor(m, 16));
    m = max(m, __shfl_xor(m, 32));
    const int iters = (m + 7) >> 3;      // 4 edges/group/iter

    int idx = beg + g;
    int c0 = col[idx     < end ? idx     : 0];
    int c1 = col[idx + 2 < end ? idx + 2 : 0];
    int c2 = col[idx + 4 < end ? idx + 4 : 0];
    int c3 = col[idx + 6 < end ? idx + 6 : 0];
    for (int j = 0; j < iters; ++j) {
        const int a0i = (idx     < end) ? c0 : PAD;
        const int a1i = (idx + 2 < end) ? c1 : PAD;
        const int a2i = (idx + 4 < end) ? c2 : PAD;
        const int a3i = (idx + 6 < end) ? c3 : PAD;
        idx += 8;
        c0 = col[idx     < end ? idx     : 0];   // prefetch next quad
        c1 = col[idx + 2 < end ? idx + 2 : 0];
        c2 = col[idx + 4 < end ? idx + 4 : 0];
        c3 = col[idx + 6 < end ? idx + 6 : 0];
        bf16x8 v0 = *(const bf16x8*)(hlin + (size_t)a0i * 64 + (fl << 3));
        bf16x8 v1 = *(const bf16x8*)(hlin + (size_t)a1i * 64 + (fl << 3));
        bf16x8 v2 = *(const bf16x8*)(hlin + (size_t)a2i * 64 + (fl << 3));
        bf16x8 v3 = *(const bf16x8*)(hlin + (size_t)a3i * 64 + (fl << 3));
#pragma unroll
        for (int k = 0; k < 8; ++k) {
            acc[k]  += s2f(v0[k]) + s2f(v1[k]);
            acc2[k] += s2f(v2[k]) + s2f(v3[k]);
        }
    }

#pragma unroll
    for (int k = 0; k < 8; ++k) acc[k] += acc2[k];
#pragma unroll
    for (int k = 0; k < 8; ++k) acc[k] += __shfl_xor(acc[k], 8);

    const float dv = dinv[nc];
    const float4 bb0 = *(const float4*)(b + (fl << 3));
    const float4 bb1 = *(const float4*)(b + (fl << 3) + 4);
    float vals[8];
    vals[0] = acc[0] * dv + bb0.x;
    vals[1] = acc[1] * dv + bb0.y;
    vals[2] = acc[2] * dv + bb0.z;
    vals[3] = acc[3] * dv + bb0.w;
    vals[4] = acc[4] * dv + bb1.x;
    vals[5] = acc[5] * dv + bb1.y;
    vals[6] = acc[6] * dv + bb1.z;
    vals[7] = acc[7] * dv + bb1.w;
    if (LEAKY) {
#pragma unroll
        for (int k = 0; k < 8; ++k) vals[k] = (vals[k] >= 0.0f) ? vals[k] : 0.01f * vals[k];
    }
    if (g == 0) {
        bf16x8 ob;
#pragma unroll
        for (int k = 0; k < 8; ++k) ob[k] = f2s(vals[k]);
        *(bf16x8*)(tile + (wave * 4 + sub) * 72 + (fl << 3)) = ob;
        if (valid) {                     // 4 nodes store in parallel: 1KB/wave
            float* op = out + (size_t)node * 64 + (fl << 3);
            f32x4 o0 = {vals[0], vals[1], vals[2], vals[3]};
            f32x4 o1 = {vals[4], vals[5], vals[6], vals[7]};
            __builtin_nontemporal_store(o0, (f32x4*)op);   // out never re-read
            __builtin_nontemporal_store(o1, (f32x4*)(op + 4));
        }
    }
    __syncthreads();

    // --- GEMM epilogue: hout[16 x DOUTN] = dinv * (tile @ WTn) ---
    const int q = sub;                   // lane>>4
    const int l16 = lane & 15;
    if (DOUTN == 64 || wave < 2) {
        bf16x8 a0 = *(const bf16x8*)(tile + l16 * 72 + q * 8);
        bf16x8 a1 = *(const bf16x8*)(tile + l16 * 72 + 32 + q * 8);
        const bf16* wrow = WTn + (size_t)(wave * 16 + l16) * 64 + q * 8;
        bf16x8 b0 = *(const bf16x8*)(wrow);
        bf16x8 b1 = *(const bf16x8*)(wrow + 32);
        f32x4 c = {0.f, 0.f, 0.f, 0.f};
        c = __builtin_amdgcn_mfma_f32_16x16x32_bf16(a0, b0, c, 0, 0, 0);
        c = __builtin_amdgcn_mfma_f32_16x16x32_bf16(a1, b1, c, 0, 0, 0);
#pragma unroll
        for (int r = 0; r < 4; ++r) {
            int rr = base + q * 4 + r;
            if (rr < n)
                hout[(size_t)rr * DOUTN + wave * 16 + l16] = __float2bfloat16(c[r] * dinv[rr]);
        }
    }
}

// --- Pull aggregation, 32 feats: 4 lanes/edge x dwordx4 (16B/lane). -------
// One gather instruction = 16 edges / 1KB (vs 8 edges before): halves the
// request/instruction count for the same sector traffic. Lane map: sub =
// node slot 0..3, eg = edge group 0..3, fl = feat-lane 0..3 (8 feats each).
// 2-deep unroll keeps 2KB in flight; butterfly = xor 4 + xor 8.
__global__ __launch_bounds__(256, 8)
void agg32_kernel(const int* __restrict__ row_ptr, const int* __restrict__ deg,
                  const int* __restrict__ col, const bf16* __restrict__ hlin,
                  const float* __restrict__ dinv, const float* __restrict__ b,
                  float* __restrict__ out, int n) {
    const int wid = (blockIdx.x * blockDim.x + threadIdx.x) >> 6;
    const int lane = threadIdx.x & 63;
    const int sub = lane >> 4;           // node slot 0..3
    const int eg = (lane >> 2) & 3;      // edge group 0..3
    const int fl = lane & 3;             // feat lane: feats fl*8..+7 (16B)
    const int node = wid * 4 + sub;
    const int PAD = 2 * n;               // zero row (32-feat layout)

    const bool valid = node < n;
    const int nc = valid ? node : n - 1;
    const int beg = row_ptr[nc];
    const int dg = valid ? deg[nc] : 0;
    const int end = beg + dg;

    float acc[8], acc2[8];
    {   // self loop: eg==0 lanes read own row (4 x 16B = 64B); others PAD
        int c0 = (valid && eg == 0) ? node : PAD;
        bf16x8 sv = *(const bf16x8*)(hlin + (size_t)c0 * 32 + (fl << 3));
#pragma unroll
        for (int k = 0; k < 8; ++k) { acc[k] = s2f(sv[k]); acc2[k] = 0.0f; }
    }

    int m = dg;
    m = max(m, __shfl_xor(m, 16));
    m = max(m, __shfl_xor(m, 32));
    const int iters = (m + 7) >> 3;      // 2 edges/group/iter x 4 groups

    int idx = beg + eg;                  // group's slots: idx, idx+4, idx+8...
    int c0 = col[idx     < end ? idx     : 0];
    int c1 = col[idx + 4 < end ? idx + 4 : 0];
    for (int j = 0; j < iters; ++j) {
        const int a0 = (idx     < end) ? c0 : PAD;
        const int a1 = (idx + 4 < end) ? c1 : PAD;
        idx += 8;
        c0 = col[idx     < end ? idx     : 0];   // prefetch next pair
        c1 = col[idx + 4 < end ? idx + 4 : 0];
        bf16x8 v0 = *(const bf16x8*)(hlin + (size_t)a0 * 32 + (fl << 3));
        bf16x8 v1 = *(const bf16x8*)(hlin + (size_t)a1 * 32 + (fl << 3));
#pragma unroll
        for (int k = 0; k < 8; ++k) { acc[k] += s2f(v0[k]); acc2[k] += s2f(v1[k]); }
    }

    // merge dual accumulators, then combine 4 edge groups (lane bits 2,3)
#pragma unroll
    for (int k = 0; k < 8; ++k) acc[k] += acc2[k];
#pragma unroll
    for (int k = 0; k < 8; ++k) acc[k] += __shfl_xor(acc[k], 4);
#pragma unroll
    for (int k = 0; k < 8; ++k) acc[k] += __shfl_xor(acc[k], 8);

    const float dv = dinv[nc];
    const float4 bb0 = *(const float4*)(b + (fl << 3));
    const float4 bb1 = *(const float4*)(b + (fl << 3) + 4);
    float vals[8];
    vals[0] = acc[0] * dv + bb0.x;
    vals[1] = acc[1] * dv + bb0.y;
    vals[2] = acc[2] * dv + bb0.z;
    vals[3] = acc[3] * dv + bb0.w;
    vals[4] = acc[4] * dv + bb1.x;
    vals[5] = acc[5] * dv + bb1.y;
    vals[6] = acc[6] * dv + bb1.z;
    vals[7] = acc[7] * dv + bb1.w;
    if (valid && eg == 0) {              // 4 fl-lanes x 32B = 128B row per node
        float* op = out + (size_t)node * 32 + (fl << 3);
        f32x4 o0 = {vals[0], vals[1], vals[2], vals[3]};
        f32x4 o1 = {vals[4], vals[5], vals[6], vals[7]};
        __builtin_nontemporal_store(o0, (f32x4*)op);
        __builtin_nontemporal_store(o1, (f32x4*)(op + 4));
    }
}

extern "C" void kernel_launch(void* const* d_in, const int* in_sizes, int n_in,
                              void* d_out, int out_size, void* d_ws, size_t ws_size,
                              hipStream_t stream) {
    const float* x  = (const float*)d_in[0];
    const int*   ei = (const int*)d_in[1];
    const float* W1 = (const float*)d_in[2];
    const float* b1 = (const float*)d_in[3];
    const float* W2 = (const float*)d_in[4];
    const float* b2 = (const float*)d_in[5];
    const float* W3 = (const float*)d_in[6];
    const float* b3 = (const float*)d_in[7];
    float* out = (float*)d_out;

    const int N = in_sizes[0] / 64;   // 100000
    const int E = in_sizes[1] / 2;    // 1600000
    const int* src = ei;
    const int* dst = ei + E;

    const int NB  = (N + 255) >> 8;           // buckets (<=512 for N<=131072)
    const int EPB = (E + NBLK - 1) / NBLK;    // edges per partition block

    char* w = (char*)d_ws;
    auto take = [&](size_t bytes) { char* p = w; w += (bytes + 15) & ~(size_t)15; return p; };
    int*   col       = (int*)take((size_t)E * 4);
    int*   ssd       = (int*)take((size_t)E * 4);   // packed (src<<8)|(dst&255)
    bf16*  hlinA     = (bf16*)take(((size_t)N * 64 + 64) * 2);  // +64 hw: PAD row
    bf16*  hlinB     = (bf16*)take(((size_t)N * 64 + 64) * 2);  // +64 hw: PAD row
    bf16*  WT1       = (bf16*)take(64 * 64 * 2);
    bf16*  WT2       = (bf16*)take(64 * 64 * 2);
    bf16*  WT3       = (bf16*)take(32 * 64 * 2);
    int*   deg       = (int*)take((size_t)N * 4);
    int*   row_ptr   = (int*)take((size_t)N * 4);
    float* dinv      = (float*)take((size_t)N * 4);
    int*   blockhist = (int*)take((size_t)NB * NBLK * 4);
    int*   btotal    = (int*)take((size_t)SCAN2_T * 4);

    float* out0 = out;
    float* out1 = out + (size_t)N * 64;
    float* out2 = out + (size_t)N * 128;

    const int fusedBlocks = (N + 15) / 16;    // 16 nodes per block (4 waves x 4)
    const int aggWaves = (N + 3) / 4;
    const int aggBlocks = (aggWaves * 64 + BLK - 1) / BLK;

    // --- build + weights + PAD (merged): 7 total dispatches ---
    bucket_histw<<<NBLK + 41, BLK, 0, stream>>>(
        dst, blockhist, W1, W2, W3, WT1, WT2, WT3,
        hlinA + (size_t)N * 64, hlinB + (size_t)N * 64, E, EPB, NB);
    colscan_kernel<<<NB, SCAN2_T, 0, stream>>>(blockhist, btotal);
    bucket_scatter<<<NBLK, BLK, 0, stream>>>(src, dst, blockhist, btotal, ssd, E, EPB, NB);
    bucket_csr_gemm<<<NB, BLK, 0, stream>>>(ssd, btotal, col, deg, row_ptr, dinv,
                                            x, WT1, hlinA, N, E, NB);

    // --- fused: agg(hlinA)->out0 + GEMM(W2)->hlinB ---
    agg_gemm_kernel<64, true><<<fusedBlocks, BLK, 0, stream>>>(
        row_ptr, deg, col, hlinA, dinv, b1, out0, WT2, hlinB, N);

    // --- fused: agg(hlinB)->out1 + GEMM(W3)->hlinA (32-col) ---
    agg_gemm_kernel<32, true><<<fusedBlocks, BLK, 0, stream>>>(
        row_ptr, deg, col, hlinB, dinv, b2, out1, WT3, hlinA, N);

    // --- layer 3 agg: out2 = agg(hlinA 32-col) + b3 ---
    agg32_kernel<<<aggBlocks, BLK, 0, stream>>>(
        row_ptr, deg, col, hlinA, dinv, b3, out2, N);
}